// Round 11
// baseline (1423.736 us; speedup 1.0000x reference)
//
#include <hip/hip_runtime.h>
#include <math.h>

// ExpressionPerformer: B=16,G=2048,D=256,H=8,dh=32,FFN=1024,L=4
// Round-20 (= R19 + three dispatch-graph fusions, compute loops untouched):
//  - embed_ln: embed + layer-0 LN1 in one kernel (wave holds full row; shuffle
//    stats; writes h AND tiled hn). Replaces embed_kernel + ln_tiled.
//  - attn_chunk_kv absorbs attn_prefix: after each block's St/Zc stores,
//    __threadfence() + device-scope atomicAdd(cnt[bh]); the 8th-arriving
//    block (old==28) performs that bh's exclusive prefix over St (1024 pos,
//    4-stream ILP) and Zc. Identical summation order -> bit-identical.
//    cnt zeroed via hipMemsetAsync (graph-capture safe, re-zeroed per replay).
//  - ffn_fused epilogue optionally computes out = h_new @ Wout + bout on the
//    last layer (wave owns full rows; float4 Wout + shuffle reduce).
//    Replaces out_proj.
//  - Dispatches 27 -> 18.

#define GG 2048
#define DD 256
#define NROWS 32768
#define NC 32
#define CS 64

typedef __attribute__((ext_vector_type(8))) short bf16x8;
typedef __attribute__((ext_vector_type(4))) float f32x4;

struct FalseT { static constexpr bool value = false; };
struct TrueT  { static constexpr bool value = true;  };

__device__ __forceinline__ short f2bf(float f) {
  union { float f; unsigned u; } v; v.f = f;
  unsigned r = v.u + 0x7FFFu + ((v.u >> 16) & 1u);
  return (short)(r >> 16);
}
__device__ __forceinline__ float bf2f(short s) {
  union { unsigned u; float f; } v; v.u = ((unsigned)(unsigned short)s) << 16;
  return v.f;
}
__device__ __forceinline__ void gld16(const short* g, short* l) {
  __builtin_amdgcn_global_load_lds(
      (const __attribute__((address_space(1))) void*)g,
      (__attribute__((address_space(3))) void*)l, 16, 0, 0);
}
__device__ __forceinline__ float fast_gelu(float x) {
  float y = 1.595769122f * (x + 0.044715f * x * x * x);
  return x / (1.0f + __expf(-y));
}

// ---------------- embed + layer-0 LN1 ---------------------------------------
__global__ __launch_bounds__(256) void embed_ln(
    const float* __restrict__ x, const float* __restrict__ ge,
    const float* __restrict__ invf, const float* __restrict__ gamma,
    const float* __restrict__ beta, float* __restrict__ h,
    short* __restrict__ hnT) {
  int bg = blockIdx.x * 4 + (threadIdx.x >> 6);
  int g = bg & (GG - 1);
  int lane = threadIdx.x & 63;
  float xv = x[bg];
  int d = lane * 4;
  float4 e;
  if (lane < 32) {
    float4 f = *(const float4*)&invf[d];
    e.x = sinf(xv * f.x); e.y = sinf(xv * f.y);
    e.z = sinf(xv * f.z); e.w = sinf(xv * f.w);
  } else {
    float4 f = *(const float4*)&invf[d - 128];
    e.x = cosf(xv * f.x); e.y = cosf(xv * f.y);
    e.z = cosf(xv * f.z); e.w = cosf(xv * f.w);
  }
  if (xv == -10.0f) { e.x = 0.f; e.y = 0.f; e.z = 0.f; e.w = 0.f; }
  float4 gv = *(const float4*)&ge[(size_t)g * DD + d];
  float4 o; o.x = gv.x + e.x; o.y = gv.y + e.y; o.z = gv.z + e.z; o.w = gv.w + e.w;
  *(float4*)&h[(size_t)bg * DD + d] = o;
  // LN over the row (one wave = one row, 4 elems/lane)
  float s = o.x + o.y + o.z + o.w;
  float s2 = o.x * o.x + o.y * o.y + o.z * o.z + o.w * o.w;
  s += __shfl_xor(s, 1); s += __shfl_xor(s, 2); s += __shfl_xor(s, 4);
  s += __shfl_xor(s, 8); s += __shfl_xor(s, 16); s += __shfl_xor(s, 32);
  s2 += __shfl_xor(s2, 1); s2 += __shfl_xor(s2, 2); s2 += __shfl_xor(s2, 4);
  s2 += __shfl_xor(s2, 8); s2 += __shfl_xor(s2, 16); s2 += __shfl_xor(s2, 32);
  float mn = s * (1.0f / 256.0f);
  float rstd = rsqrtf(s2 * (1.0f / 256.0f) - mn * mn + 1e-5f);
  float4 gm = *(const float4*)&gamma[d];
  float4 bt = *(const float4*)&beta[d];
  short4 pk;
  pk.x = f2bf((o.x - mn) * rstd * gm.x + bt.x);
  pk.y = f2bf((o.y - mn) * rstd * gm.y + bt.y);
  pk.z = f2bf((o.z - mn) * rstd * gm.z + bt.z);
  pk.w = f2bf((o.w - mn) * rstd * gm.w + bt.w);
  // tiled hn: k = d..d+3 -> kb=d>>5, kc8=(d>>3)&3, elem=d&7
  short* tb = hnT + (size_t)(bg >> 7) * 32768 + (size_t)(d >> 5) * 4096 +
              ((((d >> 3) & 3) * 128) + (bg & 127)) * 8 + (d & 7);
  *(short4*)tb = pk;
}

// ---------------- weight convert+transpose -> TILED --------------------------
__global__ __launch_bounds__(256) void prep_weights(
    const float* __restrict__ Wq, const float* __restrict__ Wk,
    const float* __restrict__ Wv, const float* __restrict__ WU,
    const float* __restrict__ WV,
    short* __restrict__ TQ, short* __restrict__ TK, short* __restrict__ TV,
    short* __restrict__ TU, short* __restrict__ TVd) {
  int zz = blockIdx.z, l = blockIdx.y;
  const float* src; short* dst; int Kd, Nd;
  if (zz == 0) { src = Wq; dst = TQ; Kd = 256; Nd = 256; }
  else if (zz == 1) { src = Wk; dst = TK; Kd = 256; Nd = 256; }
  else if (zz == 2) { src = Wv; dst = TV; Kd = 256; Nd = 256; }
  else if (zz == 3) { src = WU; dst = TU; Kd = 256; Nd = 1024; }
  else { src = WV; dst = TVd; Kd = 1024; Nd = 256; }
  int tot = Kd * Nd;
  int e = blockIdx.x * 256 + threadIdx.x;
  if (e >= tot) return;
  int t = e >> 12;
  int cslot = (e >> 3) & 511;
  int elem = e & 7;
  int kc8 = cslot >> 7, rn = cslot & 127;
  int nKb = Kd >> 5;
  int nt = t / nKb, kb = t - nt * nKb;
  int n = nt * 128 + rn, k = kb * 32 + kc8 * 8 + elem;
  dst[(size_t)l * tot + e] = f2bf(src[(size_t)l * tot + (size_t)k * Nd + n]);
}

// ---------------- bf16 MFMA GEMM (tiled operands, compile-time K) -------------
template <int K, int EPI>
__global__ __launch_bounds__(256) void gemm_t(
    const short* __restrict__ A, const short* __restrict__ B0,
    const short* __restrict__ B1, const short* __restrict__ B2,
    const float* __restrict__ bias0, const float* __restrict__ bias1,
    const float* __restrict__ bias2,
    short* __restrict__ o0, short* __restrict__ o1, short* __restrict__ o2,
    float* __restrict__ outf, int N) {
  __shared__ __align__(16) short L[24576];  // 48KB
  constexpr int nIter = K / 32;
  int z = blockIdx.z;
  const short* Bt = (z == 0) ? B0 : (z == 1) ? B1 : B2;
  const float* bias = (z == 0) ? bias0 : (z == 1) ? bias1 : bias2;
  short* outz = (z == 0) ? o0 : (z == 1) ? o1 : o2;
  int m0 = blockIdx.x * 128, n0 = blockIdx.y * 128;
  int tid = threadIdx.x;
  int lane = tid & 63, w = tid >> 6;
  int q = lane >> 4, r = lane & 15;
  int wm = (w >> 1) * 64, wn = (w & 1) * 64;
  const short* At = A + (size_t)blockIdx.x * nIter * 4096;
  const short* Btl = Bt + (size_t)blockIdx.y * nIter * 4096;
  f32x4 vzero = {0.f, 0.f, 0.f, 0.f};
  f32x4 acc[4][4];
#pragma unroll
  for (int i = 0; i < 4; ++i)
#pragma unroll
    for (int j = 0; j < 4; ++j) acc[i][j] = vzero;

  int c0 = tid * 8, c1 = (tid + 256) * 8;
#pragma unroll
  for (int g = 0; g < 3; ++g) {
    gld16(At + g * 4096 + c0, &L[g * 4096 + c0]);
    gld16(At + g * 4096 + c1, &L[g * 4096 + c1]);
    gld16(Btl + g * 4096 + c0, &L[12288 + g * 4096 + c0]);
    gld16(Btl + g * 4096 + c1, &L[12288 + g * 4096 + c1]);
  }

  int abase = (q * 128 + wm + r) * 8;
  int bbase = (q * 128 + wn + r) * 8;

#pragma unroll
  for (int gi = 0; gi < nIter; ++gi) {
    const int rem = nIter - 1 - gi;
    if (rem >= 2)      __builtin_amdgcn_s_waitcnt(0x0f78);  // vmcnt(8)
    else if (rem == 1) __builtin_amdgcn_s_waitcnt(0x0f74);  // vmcnt(4)
    else               __builtin_amdgcn_s_waitcnt(0x0f70);  // vmcnt(0)
    __builtin_amdgcn_s_barrier();
    __builtin_amdgcn_s_setprio(1);
    const int cur = gi % 3;
    const short* Asc = &L[cur * 4096];
    const short* Bsc = &L[12288 + cur * 4096];
    bf16x8 af[4], bfr[4];
#pragma unroll
    for (int mt = 0; mt < 4; ++mt)
      af[mt] = *(const bf16x8*)&Asc[abase + mt * 16 * 8];
#pragma unroll
    for (int nt = 0; nt < 4; ++nt)
      bfr[nt] = *(const bf16x8*)&Bsc[bbase + nt * 16 * 8];
#pragma unroll
    for (int mt = 0; mt < 4; ++mt)
#pragma unroll
      for (int nt = 0; nt < 4; ++nt)
        acc[mt][nt] = __builtin_amdgcn_mfma_f32_16x16x32_bf16(bfr[nt], af[mt], acc[mt][nt], 0, 0, 0);
    __builtin_amdgcn_s_setprio(0);
    __builtin_amdgcn_s_waitcnt(0xc07f);  // lgkmcnt(0)
    __builtin_amdgcn_s_barrier();
    if (gi + 3 < nIter) {
      size_t kn = (size_t)(gi + 3) * 4096;
      gld16(At + kn + c0, &L[cur * 4096 + c0]);
      gld16(At + kn + c1, &L[cur * 4096 + c1]);
      gld16(Btl + kn + c0, &L[12288 + cur * 4096 + c0]);
      gld16(Btl + kn + c1, &L[12288 + cur * 4096 + c1]);
    }
  }

  float4 bias4[4];
#pragma unroll
  for (int nt = 0; nt < 4; ++nt) bias4[nt] = *(const float4*)&bias[n0 + wn + nt * 16 + q * 4];

  if (EPI == 0) {
    short* T = L;
#pragma unroll
    for (int mt = 0; mt < 4; ++mt) {
      int ml = wm + mt * 16 + r;
#pragma unroll
      for (int nt = 0; nt < 4; ++nt) {
        f32x4 v = acc[mt][nt];
        v[0] += bias4[nt].x; v[1] += bias4[nt].y; v[2] += bias4[nt].z; v[3] += bias4[nt].w;
        if (z < 2) { v[0] *= v[0]; v[1] *= v[1]; v[2] *= v[2]; v[3] *= v[3]; }
        short4 pk; pk.x = f2bf(v[0]); pk.y = f2bf(v[1]); pk.z = f2bf(v[2]); pk.w = f2bf(v[3]);
        *(short4*)&T[ml * 132 + wn + nt * 16 + q * 4] = pk;
      }
    }
    __syncthreads();
#pragma unroll
    for (int t2 = 0; t2 < 2; ++t2) {
      int task = tid + t2 * 256;
      int row = task & 127, hl = task >> 7;
      size_t obase = ((size_t)((n0 >> 5) + hl) * NROWS + m0 + row) * 32;
#pragma unroll
      for (int j = 0; j < 4; ++j)
        *(bf16x8*)&outz[obase + j * 8] = *(const bf16x8*)&T[row * 132 + hl * 32 + j * 8];
    }
  } else if (EPI == 1) {
#pragma unroll
    for (int mt = 0; mt < 4; ++mt) {
      int ml = wm + mt * 16 + r;
#pragma unroll
      for (int nt = 0; nt < 4; ++nt) {
        f32x4 v = acc[mt][nt];
        v[0] += bias4[nt].x; v[1] += bias4[nt].y; v[2] += bias4[nt].z; v[3] += bias4[nt].w;
#pragma unroll
        for (int e = 0; e < 4; ++e) v[e] = fast_gelu(v[e]);
        short4 o; o.x = f2bf(v[0]); o.y = f2bf(v[1]); o.z = f2bf(v[2]); o.w = f2bf(v[3]);
        int n = n0 + wn + nt * 16 + q * 4;
        size_t ti = ((size_t)blockIdx.x * (N >> 5) + (n >> 5)) * 4096 +
                    (size_t)(((n >> 3) & 3) << 10) + (ml << 3) + (n & 7);
        *(short4*)&outz[ti] = o;
      }
    }
  } else {
    float* TF = (float*)L;
#pragma unroll
    for (int half = 0; half < 2; ++half) {
      __syncthreads();
      if ((w & 1) == half) {
#pragma unroll
        for (int mt = 0; mt < 4; ++mt) {
          int ml = wm + mt * 16 + r;
#pragma unroll
          for (int nt = 0; nt < 4; ++nt) {
            f32x4 v = acc[mt][nt];
            v[0] += bias4[nt].x; v[1] += bias4[nt].y; v[2] += bias4[nt].z; v[3] += bias4[nt].w;
            *(f32x4*)&TF[ml * 68 + nt * 16 + q * 4] = v;
          }
        }
      }
      __syncthreads();
      int row = tid >> 1, col = (tid & 1) * 32;
      size_t hoff = (size_t)(m0 + row) * N + n0 + half * 64 + col;
#pragma unroll
      for (int j = 0; j < 8; ++j) {
        float4 add = *(const float4*)&TF[row * 68 + col + j * 4];
        float4 cur4 = *(float4*)&outf[hoff + j * 4];
        cur4.x += add.x; cur4.y += add.y; cur4.z += add.z; cur4.w += add.w;
        *(float4*)&outf[hoff + j * 4] = cur4;
      }
    }
  }
}

// ---------------- fused FFN: h += gelu(hn@WU+bU)@WV + bV, LN1[l+1] / out -----
__global__ __launch_bounds__(512) void ffn_fused(
    const short* __restrict__ A, const short* __restrict__ TUw,
    const short* __restrict__ TVw, const float* __restrict__ bUp,
    const float* __restrict__ bVp, float* __restrict__ h,
    short* __restrict__ hnT, const float* __restrict__ ln1g,
    const float* __restrict__ ln1b, const float* __restrict__ Woutp,
    const float* __restrict__ boutp, float* __restrict__ outp) {
  __shared__ __align__(16) short L[81920];  // 160KB
  int tid = threadIdx.x;
  int lane = tid & 63, w = tid >> 6;
  int q = lane >> 4, r = lane & 15;
  int wmU = (w >> 2) * 64, wnU = (w & 3) * 32;
  int wmD = (w >> 2) * 64, wnD = (w & 3) * 64;
  const short* At = A + (size_t)blockIdx.x * 32768;

#pragma unroll
  for (int i = 0; i < 8; ++i)
    gld16(At + (i * 512 + tid) * 8, &L[(i * 512 + tid) * 8]);

  auto issueFor = [&](int t) {
    short* dst = &L[49152 + (t & 1) * 16384];
    int ss = t >> 2, pp = t & 3;
    if (pp < 2) {
      const short* g0 = TUw + ((size_t)ss * 8 + pp * 4) * 4096;
#pragma unroll
      for (int i = 0; i < 4; ++i)
        gld16(g0 + (i * 512 + tid) * 8, dst + (i * 512 + tid) * 8);
    } else {
      int kbg0 = ss * 4 + (pp - 2) * 2;
#pragma unroll
      for (int kl = 0; kl < 2; ++kl) {
        gld16(TVw + (size_t)(kbg0 + kl) * 4096 + tid * 8,
              dst + kl * 8192 + tid * 8);
        gld16(TVw + (size_t)(32 + kbg0 + kl) * 4096 + tid * 8,
              dst + kl * 8192 + 4096 + tid * 8);
      }
    }
  };

  issueFor(0); issueFor(1);

  f32x4 vzero = {0.f, 0.f, 0.f, 0.f};
  f32x4 accm[4][2], acco[4][4];
#pragma unroll
  for (int mt = 0; mt < 4; ++mt) {
#pragma unroll
    for (int nt = 0; nt < 2; ++nt) accm[mt][nt] = vzero;
#pragma unroll
    for (int nt = 0; nt < 4; ++nt) acco[mt][nt] = vzero;
  }
  float4 b4[2];

  auto slice = [&](int s, auto lastc) {
    constexpr bool LAST = decltype(lastc)::value;
#pragma unroll
    for (int p = 0; p < 2; ++p) {
      int sig = s * 4 + p;
      __builtin_amdgcn_s_waitcnt(0x0f74);  // vmcnt(4)
      __builtin_amdgcn_s_barrier();
      const short* Ws = &L[49152 + (sig & 1) * 16384];
#pragma unroll
      for (int kl = 0; kl < 4; ++kl) {
        int kb = p * 4 + kl;
        bf16x8 af[4], bfr[2];
#pragma unroll
        for (int mt = 0; mt < 4; ++mt)
          af[mt] = *(const bf16x8*)&L[kb * 4096 + (q * 128 + wmU + mt * 16 + r) * 8];
#pragma unroll
        for (int nt = 0; nt < 2; ++nt)
          bfr[nt] = *(const bf16x8*)&Ws[kl * 4096 + (q * 128 + wnU + nt * 16 + r) * 8];
#pragma unroll
        for (int mt = 0; mt < 4; ++mt)
#pragma unroll
          for (int nt = 0; nt < 2; ++nt)
            accm[mt][nt] = __builtin_amdgcn_mfma_f32_16x16x32_bf16(
                bfr[nt], af[mt], accm[mt][nt], 0, 0, 0);
      }
      if (p == 1) {
#pragma unroll
        for (int mt = 0; mt < 4; ++mt) {
          int row = wmU + mt * 16 + r;
#pragma unroll
          for (int nt = 0; nt < 2; ++nt) {
            f32x4 v = accm[mt][nt];
            float4 bb = b4[nt];
            v[0] += bb.x; v[1] += bb.y; v[2] += bb.z; v[3] += bb.w;
            short4 pk;
            pk.x = f2bf(fast_gelu(v[0])); pk.y = f2bf(fast_gelu(v[1]));
            pk.z = f2bf(fast_gelu(v[2])); pk.w = f2bf(fast_gelu(v[3]));
            int kc8 = 2 * nt + (q >> 1);
            *(short4*)&L[32768 + (w & 3) * 4096 + (kc8 * 128 + row) * 8 + (q & 1) * 4] = pk;
            accm[mt][nt] = vzero;
          }
        }
      }
      __builtin_amdgcn_s_waitcnt(0xc07f);  // lgkmcnt(0)
      __builtin_amdgcn_s_barrier();
      if (p == 0) {
        b4[0] = *(const float4*)&bUp[s * 128 + wnU + q * 4];
        b4[1] = *(const float4*)&bUp[s * 128 + wnU + 16 + q * 4];
      }
      if (sig + 2 < 32) issueFor(sig + 2);
    }
#pragma unroll
    for (int p2 = 0; p2 < 2; ++p2) {
      int sig = s * 4 + 2 + p2;
      if (LAST && p2 == 1) __builtin_amdgcn_s_waitcnt(0x0f70);  // vmcnt(0)
      else                 __builtin_amdgcn_s_waitcnt(0x0f74);  // vmcnt(4)
      __builtin_amdgcn_s_barrier();
      const short* Ws = &L[49152 + (sig & 1) * 16384];
#pragma unroll
      for (int kl = 0; kl < 2; ++kl) {
        int mtile = p2 * 2 + kl;
        bf16x8 am[4], bvf[4];
#pragma unroll
        for (int mt = 0; mt < 4; ++mt)
          am[mt] = *(const bf16x8*)&L[32768 + mtile * 4096 + (q * 128 + wmD + mt * 16 + r) * 8];
#pragma unroll
        for (int nt = 0; nt < 4; ++nt)
          bvf[nt] = *(const bf16x8*)&Ws[kl * 8192 + (wnD >> 7) * 4096 +
                                        (q * 128 + (wnD & 127) + nt * 16 + r) * 8];
#pragma unroll
        for (int mt = 0; mt < 4; ++mt)
#pragma unroll
          for (int nt = 0; nt < 4; ++nt)
            acco[mt][nt] = __builtin_amdgcn_mfma_f32_16x16x32_bf16(
                bvf[nt], am[mt], acco[mt][nt], 0, 0, 0);
      }
      __builtin_amdgcn_s_waitcnt(0xc07f);  // lgkmcnt(0)
      __builtin_amdgcn_s_barrier();
      if (sig + 2 < 32) issueFor(sig + 2);
    }
  };

  for (int s = 0; s < 7; ++s) slice(s, FalseT{});
  slice(7, TrueT{});

  // ---- epilogue: out += bV; TF[128][268]; wave-owns-row h RMW; LN1 or out ----
  float* TF = (float*)L;
  float* MEAN = (float*)&L[68608];
  float* RSTD = MEAN + 128;
  float4 bv4[4];
#pragma unroll
  for (int nt = 0; nt < 4; ++nt) bv4[nt] = *(const float4*)&bVp[wnD + nt * 16 + q * 4];
#pragma unroll
  for (int mt = 0; mt < 4; ++mt) {
    int row = wmD + mt * 16 + r;
#pragma unroll
    for (int nt = 0; nt < 4; ++nt) {
      f32x4 v = acco[mt][nt];
      v[0] += bv4[nt].x; v[1] += bv4[nt].y; v[2] += bv4[nt].z; v[3] += bv4[nt].w;
      *(f32x4*)&TF[row * 268 + wnD + nt * 16 + q * 4] = v;
    }
  }
  __syncthreads();
  float bo = outp ? boutp[0] : 0.f;
#pragma unroll
  for (int p = 0; p < 16; ++p) {
    int row = p * 8 + w;
    int col = lane * 4;
    size_t off = ((size_t)blockIdx.x * 128 + row) * DD + col;
    float4 ad = *(const float4*)&TF[row * 268 + col];
    float4 cv = *(float4*)&h[off];
    cv.x += ad.x; cv.y += ad.y; cv.z += ad.z; cv.w += ad.w;
    *(float4*)&h[off] = cv;
    if (ln1g) {
      *(float4*)&TF[row * 268 + col] = cv;
      float s = cv.x + cv.y + cv.z + cv.w;
      float s2 = cv.x * cv.x + cv.y * cv.y + cv.z * cv.z + cv.w * cv.w;
      s += __shfl_xor(s, 1); s += __shfl_xor(s, 2); s += __shfl_xor(s, 4);
      s += __shfl_xor(s, 8); s += __shfl_xor(s, 16); s += __shfl_xor(s, 32);
      s2 += __shfl_xor(s2, 1); s2 += __shfl_xor(s2, 2); s2 += __shfl_xor(s2, 4);
      s2 += __shfl_xor(s2, 8); s2 += __shfl_xor(s2, 16); s2 += __shfl_xor(s2, 32);
      if (lane == 0) {
        float mn = s * (1.0f / 256.0f);
        MEAN[row] = mn;
        RSTD[row] = rsqrtf(s2 * (1.0f / 256.0f) - mn * mn + 1e-5f);
      }
    }
    if (outp) {  // fused final projection (last layer)
      float4 w4 = *(const float4*)&Woutp[col];
      float so = cv.x * w4.x + cv.y * w4.y + cv.z * w4.z + cv.w * w4.w;
      so += __shfl_xor(so, 1); so += __shfl_xor(so, 2); so += __shfl_xor(so, 4);
      so += __shfl_xor(so, 8); so += __shfl_xor(so, 16); so += __shfl_xor(so, 32);
      if (lane == 0) outp[(size_t)blockIdx.x * 128 + row] = so + bo;
    }
  }
  if (ln1g) {
    __syncthreads();
    int row2 = tid & 127, kc8g = tid >> 7;
    float mn = MEAN[row2], rstd = RSTD[row2];
    short* tb = hnT + (size_t)blockIdx.x * 32768 + (kc8g * 128 + row2) * 8;
#pragma unroll
    for (int kb = 0; kb < 8; ++kb) {
      int k0 = kb * 32 + kc8g * 8;
      float4 x0 = *(const float4*)&TF[row2 * 268 + k0];
      float4 x1 = *(const float4*)&TF[row2 * 268 + k0 + 4];
      float4 g0 = *(const float4*)&ln1g[k0], g1 = *(const float4*)&ln1g[k0 + 4];
      float4 b0 = *(const float4*)&ln1b[k0], b1 = *(const float4*)&ln1b[k0 + 4];
      bf16x8 aw;
      aw[0] = f2bf((x0.x - mn) * rstd * g0.x + b0.x);
      aw[1] = f2bf((x0.y - mn) * rstd * g0.y + b0.y);
      aw[2] = f2bf((x0.z - mn) * rstd * g0.z + b0.z);
      aw[3] = f2bf((x0.w - mn) * rstd * g0.w + b0.w);
      aw[4] = f2bf((x1.x - mn) * rstd * g1.x + b1.x);
      aw[5] = f2bf((x1.y - mn) * rstd * g1.y + b1.y);
      aw[6] = f2bf((x1.z - mn) * rstd * g1.z + b1.z);
      aw[7] = f2bf((x1.w - mn) * rstd * g1.w + b1.w);
      *(bf16x8*)&tb[(size_t)kb * 4096] = aw;
    }
  }
}

// ---------------- attention A1+A2: S_c = K^T V, z_c; fused exclusive prefix --
// Each block: 4 (bh,c) units (same bh). After St/Zc stores: fence + device
// atomicAdd(cnt[bh], 4); the block seeing old==28 performs bh's prefix
// (identical float order to the old attn_prefix kernel).
__global__ __launch_bounds__(256) void attn_chunk_kv(
    const short* __restrict__ Kb, const short* __restrict__ Vb,
    float* __restrict__ St, float* __restrict__ Zc, int* __restrict__ cnt) {
  __shared__ short Kt[4][32 * 72];
  __shared__ short Vt[4][32 * 72];
  __shared__ int sflag;
  int wid = threadIdx.x >> 6;
  int blk = blockIdx.x * 4 + wid;
  int c = blk & (NC - 1), bh = blk >> 5;
  int b = bh >> 3, hh = bh & 7;
  int lane = threadIdx.x & 63, q = lane >> 4, r = lane & 15;
  size_t rowbase = ((size_t)hh * NROWS + b * GG + c * CS + lane) * 32;
#pragma unroll
  for (int j = 0; j < 4; ++j) {
    bf16x8 kv = *(const bf16x8*)&Kb[rowbase + j * 8];
    bf16x8 vv = *(const bf16x8*)&Vb[rowbase + j * 8];
#pragma unroll
    for (int e = 0; e < 8; ++e) {
      Kt[wid][(j * 8 + e) * 72 + lane] = kv[e];
      Vt[wid][(j * 8 + e) * 72 + lane] = vv[e];
    }
  }
  __syncthreads();
  f32x4 vzero = {0.f, 0.f, 0.f, 0.f};
  f32x4 acc[2][2];
#pragma unroll
  for (int i = 0; i < 2; ++i)
#pragma unroll
    for (int j = 0; j < 2; ++j) acc[i][j] = vzero;
#pragma unroll
  for (int ks = 0; ks < 2; ++ks) {
    bf16x8 afr[2], bfr[2];
#pragma unroll
    for (int mt = 0; mt < 2; ++mt) afr[mt] = *(const bf16x8*)&Kt[wid][(mt * 16 + r) * 72 + ks * 32 + q * 8];
#pragma unroll
    for (int nt = 0; nt < 2; ++nt) bfr[nt] = *(const bf16x8*)&Vt[wid][(nt * 16 + r) * 72 + ks * 32 + q * 8];
#pragma unroll
    for (int mt = 0; mt < 2; ++mt)
#pragma unroll
      for (int nt = 0; nt < 2; ++nt)
        acc[mt][nt] = __builtin_amdgcn_mfma_f32_16x16x32_bf16(afr[mt], bfr[nt], acc[mt][nt], 0, 0, 0);
  }
  float* stp = St + ((size_t)bh * NC + c) * 1024;
#pragma unroll
  for (int mt = 0; mt < 2; ++mt)
#pragma unroll
    for (int nt = 0; nt < 2; ++nt)
      *(f32x4*)&stp[(nt * 16 + r) * 32 + mt * 16 + q * 4] = acc[mt][nt];  // St[d][f]
  if (lane < 32) {
    float s = 0.f;
#pragma unroll
    for (int j = 0; j < 8; ++j) {
      bf16x8 kr = *(const bf16x8*)&Kt[wid][lane * 72 + j * 8];
#pragma unroll
      for (int e = 0; e < 8; ++e) s += bf2f(kr[e]);
    }
    Zc[((size_t)bh * NC + c) * 32 + lane] = s;
  }

  // ---- signal completion; 8th-arriving block does the exclusive prefix ----
  __threadfence();           // release our St/Zc stores device-wide
  __syncthreads();
  if (threadIdx.x == 0) sflag = (atomicAdd(&cnt[bh], 4) == 28);
  __syncthreads();
  if (!sflag) return;
  __threadfence();           // acquire other blocks' St/Zc stores
  {
    int t = threadIdx.x;
    float* p = St + (size_t)bh * NC * 1024;
    float* p0 = p + t, *p1 = p + t + 256, *p2 = p + t + 512, *p3 = p + t + 768;
    float r0 = 0.f, r1 = 0.f, r2 = 0.f, r3 = 0.f;
#pragma unroll
    for (int c2 = 0; c2 < NC; ++c2) {
      float v0 = p0[c2 * 1024], v1 = p1[c2 * 1024];
      float v2 = p2[c2 * 1024], v3 = p3[c2 * 1024];
      p0[c2 * 1024] = r0; p1[c2 * 1024] = r1;
      p2[c2 * 1024] = r2; p3[c2 * 1024] = r3;
      r0 += v0; r1 += v1; r2 += v2; r3 += v3;
    }
    if (t < 32) {
      float rz = 0.f;
      float* pz = Zc + (size_t)bh * NC * 32 + t;
#pragma unroll
      for (int c2 = 0; c2 < NC; ++c2) { float v = pz[c2 * 32]; pz[c2 * 32] = rz; rz += v; }
    }
  }
}

// ---------------- attention B: intra-chunk + apply + fused LN2 ---------------
__global__ __launch_bounds__(512) void attn_intra(
    const short* __restrict__ Qb, const short* __restrict__ Kb,
    const short* __restrict__ Vb, const float* __restrict__ St,
    const float* __restrict__ Zc, float* __restrict__ h,
    short* __restrict__ hnT, const float* __restrict__ ln2g,
    const float* __restrict__ ln2b) {
  __shared__ __align__(16) short P[8][64 * 72];
  __shared__ short Vt[8][32 * 72];
  __shared__ float den[8][64];
  __shared__ float MEAN[64], RSTD[64];
  int wid = threadIdx.x >> 6;
  int u = blockIdx.x;
  int b = u >> 5, c = u & 31;
  int hh = wid, bh = b * 8 + hh;
  int lane = threadIdx.x & 63, q = lane >> 4, r = lane & 15;
  size_t hrow0 = (size_t)b * GG + c * CS;
  size_t qrow0 = (size_t)hh * NROWS + b * GG + c * CS;

  const float* zp = Zc + ((size_t)bh * NC + c) * 32;
  float qz = 0.f;
  {
    size_t qoff = (qrow0 + lane) * 32;
#pragma unroll
    for (int j = 0; j < 4; ++j) {
      bf16x8 qv = *(const bf16x8*)&Qb[qoff + j * 8];
#pragma unroll
      for (int e = 0; e < 8; ++e) qz += bf2f(qv[e]) * zp[j * 8 + e];
    }
  }
  den[wid][lane] = qz;

  {
    size_t voff = (qrow0 + lane) * 32;
#pragma unroll
    for (int j = 0; j < 4; ++j) {
      bf16x8 vv = *(const bf16x8*)&Vb[voff + j * 8];
#pragma unroll
      for (int e = 0; e < 8; ++e) Vt[wid][(j * 8 + e) * 72 + lane] = vv[e];
    }
  }

  bf16x8 ak[4], bqf[4];
#pragma unroll
  for (int t4 = 0; t4 < 4; ++t4) {
    ak[t4]  = *(const bf16x8*)&Kb[(qrow0 + t4 * 16 + r) * 32 + q * 8];
    bqf[t4] = *(const bf16x8*)&Qb[(qrow0 + t4 * 16 + r) * 32 + q * 8];
  }
  f32x4 vzero = {0.f, 0.f, 0.f, 0.f};
  f32x4 pacc[4][4];
#pragma unroll
  for (int mt = 0; mt < 4; ++mt)
#pragma unroll
    for (int nt = 0; nt < 4; ++nt)
      pacc[mt][nt] = __builtin_amdgcn_mfma_f32_16x16x32_bf16(ak[mt], bqf[nt], vzero, 0, 0, 0);

  float rs[4] = {0.f, 0.f, 0.f, 0.f};
#pragma unroll
  for (int nt = 0; nt < 4; ++nt) {
    int t = nt * 16 + r;
#pragma unroll
    for (int mt = 0; mt < 4; ++mt) {
      short4 pk;
#pragma unroll
      for (int rr = 0; rr < 4; ++rr) {
        int s = mt * 16 + q * 4 + rr;
        float pv = (s <= t) ? pacc[mt][nt][rr] : 0.f;
        rs[nt] += pv;
        ((short*)&pk)[rr] = f2bf(pv);
      }
      *(short4*)&P[wid][t * 72 + mt * 16 + q * 4] = pk;
    }
  }
#pragma unroll
  for (int nt = 0; nt < 4; ++nt) {
    rs[nt] += __shfl_xor(rs[nt], 16);
    rs[nt] += __shfl_xor(rs[nt], 32);
  }
  __syncthreads();
  if (lane < 16) {
#pragma unroll
    for (int nt = 0; nt < 4; ++nt) den[wid][nt * 16 + lane] += rs[nt];
  }
  __syncthreads();

  f32x4 oacc[4][2];
#pragma unroll
  for (int mt = 0; mt < 4; ++mt)
#pragma unroll
    for (int nt2 = 0; nt2 < 2; ++nt2) oacc[mt][nt2] = vzero;
  const float* stp = St + ((size_t)bh * NC + c) * 1024;
#pragma unroll
  for (int nt2 = 0; nt2 < 2; ++nt2) {
    float4 s0 = *(const float4*)&stp[(nt2 * 16 + r) * 32 + q * 8];
    float4 s1 = *(const float4*)&stp[(nt2 * 16 + r) * 32 + q * 8 + 4];
    bf16x8 bs;
    bs[0] = f2bf(s0.x); bs[1] = f2bf(s0.y); bs[2] = f2bf(s0.z); bs[3] = f2bf(s0.w);
    bs[4] = f2bf(s1.x); bs[5] = f2bf(s1.y); bs[6] = f2bf(s1.z); bs[7] = f2bf(s1.w);
#pragma unroll
    for (int mt = 0; mt < 4; ++mt)
      oacc[mt][nt2] = __builtin_amdgcn_mfma_f32_16x16x32_bf16(bqf[mt], bs, oacc[mt][nt2], 0, 0, 0);
  }
#pragma unroll
  for (int ks = 0; ks < 2; ++ks) {
    bf16x8 ap[4];
#pragma unroll
    for (int mt = 0; mt < 4; ++mt)
      ap[mt] = *(const bf16x8*)&P[wid][(mt * 16 + r) * 72 + ks * 32 + q * 8];
#pragma unroll
    for (int nt2 = 0; nt2 < 2; ++nt2) {
      bf16x8 bv_ = *(const bf16x8*)&Vt[wid][(nt2 * 16 + r) * 72 + ks * 32 + q * 8];
#pragma unroll
      for (int mt = 0; mt < 4; ++mt)
        oacc[mt][nt2] = __builtin_amdgcn_mfma_f32_16x16x32_bf16(ap[mt], bv_, oacc[mt][nt2], 0, 0, 0);
    }
  }

  // ---- epilogue: OF[64][268] f32 (aliases P); h RMW + LN2 + tiled hn ----
  float* OF = (float*)&P[0][0];
  __syncthreads();
#pragma unroll
  for (int mt = 0; mt < 4; ++mt) {
#pragma unroll
    for (int rr = 0; rr < 4; ++rr) {
      int t = mt * 16 + q * 4 + rr;
      float inv = 1.0f / (den[wid][t] + 1e-16f);
#pragma unroll
      for (int nt2 = 0; nt2 < 2; ++nt2)
        OF[t * 268 + hh * 32 + nt2 * 16 + r] = oacc[mt][nt2][rr] * inv;
    }
  }
  __syncthreads();
  int tid = threadIdx.x;
#pragma unroll
  for (int p = 0; p < 8; ++p) {
    int row = p * 8 + wid;
    int col = lane * 4;
    size_t off = (hrow0 + row) * DD + col;
    float4 ad = *(const float4*)&OF[row * 268 + col];
    float4 cv = *(float4*)&h[off];
    cv.x += ad.x; cv.y += ad.y; cv.z += ad.z; cv.w += ad.w;
    *(float4*)&h[off] = cv;
    *(float4*)&OF[row * 268 + col] = cv;
    float s = cv.x + cv.y + cv.z + cv.w;
    float s2 = cv.x * cv.x + cv.y * cv.y + cv.z * cv.z + cv.w * cv.w;
    s += __shfl_xor(s, 1); s += __shfl_xor(s, 2); s += __shfl_xor(s, 4);
    s += __shfl_xor(s, 8); s += __shfl_xor(s, 16); s += __shfl_xor(s, 32);
    s2 += __shfl_xor(s2, 1); s2 += __shfl_xor(s2, 2); s2 += __shfl_xor(s2, 4);
    s2 += __shfl_xor(s2, 8); s2 += __shfl_xor(s2, 16); s2 += __shfl_xor(s2, 32);
    if (lane == 0) {
      float mn = s * (1.0f / 256.0f);
      MEAN[row] = mn;
      RSTD[row] = rsqrtf(s2 * (1.0f / 256.0f) - mn * mn + 1e-5f);
    }
  }
  __syncthreads();
  int row2 = tid & 63, kc8g = (tid >> 6) & 3, half = tid >> 8;
  float mn = MEAN[row2], rstd = RSTD[row2];
  size_t grow = hrow0 + row2;
  short* tb = hnT + (grow >> 7) * 32768 + (kc8g * 128 + (int)(grow & 127)) * 8;
#pragma unroll
  for (int j = 0; j < 4; ++j) {
    int kb = half * 4 + j;
    int k0 = kb * 32 + kc8g * 8;
    float4 x0 = *(const float4*)&OF[row2 * 268 + k0];
    float4 x1 = *(const float4*)&OF[row2 * 268 + k0 + 4];
    float4 g0 = *(const float4*)&ln2g[k0], g1 = *(const float4*)&ln2g[k0 + 4];
    float4 b0 = *(const float4*)&ln2b[k0], b1 = *(const float4*)&ln2b[k0 + 4];
    bf16x8 aw;
    aw[0] = f2bf((x0.x - mn) * rstd * g0.x + b0.x);
    aw[1] = f2bf((x0.y - mn) * rstd * g0.y + b0.y);
    aw[2] = f2bf((x0.z - mn) * rstd * g0.z + b0.z);
    aw[3] = f2bf((x0.w - mn) * rstd * g0.w + b0.w);
    aw[4] = f2bf((x1.x - mn) * rstd * g1.x + b1.x);
    aw[5] = f2bf((x1.y - mn) * rstd * g1.y + b1.y);
    aw[6] = f2bf((x1.z - mn) * rstd * g1.z + b1.z);
    aw[7] = f2bf((x1.w - mn) * rstd * g1.w + b1.w);
    *(bf16x8*)&tb[(size_t)kb * 4096] = aw;
  }
}

extern "C" void kernel_launch(void* const* d_in, const int* in_sizes, int n_in,
                              void* d_out, int out_size, void* d_ws, size_t ws_size,
                              hipStream_t stream) {
  const float* x    = (const float*)d_in[0];
  const float* ge   = (const float*)d_in[1];
  const float* invf = (const float*)d_in[2];
  const float* Wq   = (const float*)d_in[3];
  const float* bq   = (const float*)d_in[4];
  const float* Wk   = (const float*)d_in[5];
  const float* bk   = (const float*)d_in[6];
  const float* Wv   = (const float*)d_in[7];
  const float* bv   = (const float*)d_in[8];
  const float* ln1g = (const float*)d_in[9];
  const float* ln1b = (const float*)d_in[10];
  const float* ln2g = (const float*)d_in[11];
  const float* ln2b = (const float*)d_in[12];
  const float* WU   = (const float*)d_in[13];
  const float* bU   = (const float*)d_in[14];
  const float* WV   = (const float*)d_in[15];
  const float* bV   = (const float*)d_in[16];
  const float* Wout = (const float*)d_in[17];
  const float* bout = (const float*)d_in[18];
  float* out = (float*)d_out;

  char* ws = (char*)d_ws;
  float* h   = (float*)(ws + 0);            // 33.5 MB
  short* hn  = (short*)(ws + 33554432);     // 16.8 MB (tiled)
  char*  R   = ws + 50331648;               // shared region
  short* qb  = (short*)(R + 0);             // head-major [8][32768][32]
  short* kb  = (short*)(R + 16777216);
  short* vb  = (short*)(R + 33554432);
  float* St  = (float*)(R + 50331648);
  float* Zc  = (float*)(R + 67108864);
  char*  WT  = R + 67633152;
  short* TQ  = (short*)(WT + 0);
  short* TK  = (short*)(WT + 524288);
  short* TVq = (short*)(WT + 1048576);
  short* TU  = (short*)(WT + 1572864);
  short* TVd = (short*)(WT + 3670016);
  int*   cnt = (int*)(WT + 5767168);        // 4 layers x 128 ints

  hipMemsetAsync(cnt, 0, 4 * 128 * sizeof(int), stream);
  prep_weights<<<dim3(1024, 4, 5), 256, 0, stream>>>(Wq, Wk, Wv, WU, WV, TQ, TK, TVq, TU, TVd);
  embed_ln<<<NROWS / 4, 256, 0, stream>>>(x, ge, invf, ln1g, ln1b, h, hn);

  for (int l = 0; l < 4; ++l) {
    gemm_t<256, 0><<<dim3(256, 2, 3), 256, 0, stream>>>(
        hn, TQ + l * 65536, TK + l * 65536, TVq + l * 65536,
        bq + l * 256, bk + l * 256, bv + l * 256,
        qb, kb, vb, nullptr, 256);
    attn_chunk_kv<<<1024, 256, 0, stream>>>(kb, vb, St, Zc, cnt + l * 128);
    attn_intra<<<512, 512, 0, stream>>>(qb, kb, vb, St, Zc, h,
                                        hn, ln2g + l * 256, ln2b + l * 256);
    ffn_fused<<<256, 512, 0, stream>>>(hn, TU + l * 262144, TVd + l * 262144,
                                       bU + l * 1024, bV + l * 256, h,
                                       hn,
                                       (l < 3) ? ln1g + (l + 1) * 256 : nullptr,
                                       (l < 3) ? ln1b + (l + 1) * 256 : nullptr,
                                       (l == 3) ? Wout : nullptr,
                                       (l == 3) ? bout : nullptr,
                                       (l == 3) ? out : nullptr);
  }
}

// Round 12
// 698.755 us; speedup vs baseline: 2.0375x; 2.0375x over previous
//
#include <hip/hip_runtime.h>
#include <math.h>

// ExpressionPerformer: B=16,G=2048,D=256,H=8,dh=32,FFN=1024,L=4
// Round-21 (= R20 minus the fence fusion):
//  - REVERTED attn_prefix fusion. R20's per-block __threadfence() + device
//    atomic forced an L2 writeback per block (per-XCD L2 non-coherent) ->
//    attn_chunk_kv 10us -> 217us + 21ms outlier, total 710 -> 1424. Standalone
//    attn_prefix kernel restored; NO device-scope fences anywhere.
//  - KEPT embed_ln (embed + layer-0 LN1 in one kernel).
//  - KEPT out = h@Wout+bout fused into last-layer ffn epilogue.
//  - Dispatches: 22.

#define GG 2048
#define DD 256
#define NROWS 32768
#define NC 32
#define CS 64

typedef __attribute__((ext_vector_type(8))) short bf16x8;
typedef __attribute__((ext_vector_type(4))) float f32x4;

struct FalseT { static constexpr bool value = false; };
struct TrueT  { static constexpr bool value = true;  };

__device__ __forceinline__ short f2bf(float f) {
  union { float f; unsigned u; } v; v.f = f;
  unsigned r = v.u + 0x7FFFu + ((v.u >> 16) & 1u);
  return (short)(r >> 16);
}
__device__ __forceinline__ float bf2f(short s) {
  union { unsigned u; float f; } v; v.u = ((unsigned)(unsigned short)s) << 16;
  return v.f;
}
__device__ __forceinline__ void gld16(const short* g, short* l) {
  __builtin_amdgcn_global_load_lds(
      (const __attribute__((address_space(1))) void*)g,
      (__attribute__((address_space(3))) void*)l, 16, 0, 0);
}
__device__ __forceinline__ float fast_gelu(float x) {
  float y = 1.595769122f * (x + 0.044715f * x * x * x);
  return x / (1.0f + __expf(-y));
}

// ---------------- embed + layer-0 LN1 ---------------------------------------
__global__ __launch_bounds__(256) void embed_ln(
    const float* __restrict__ x, const float* __restrict__ ge,
    const float* __restrict__ invf, const float* __restrict__ gamma,
    const float* __restrict__ beta, float* __restrict__ h,
    short* __restrict__ hnT) {
  int bg = blockIdx.x * 4 + (threadIdx.x >> 6);
  int g = bg & (GG - 1);
  int lane = threadIdx.x & 63;
  float xv = x[bg];
  int d = lane * 4;
  float4 e;
  if (lane < 32) {
    float4 f = *(const float4*)&invf[d];
    e.x = sinf(xv * f.x); e.y = sinf(xv * f.y);
    e.z = sinf(xv * f.z); e.w = sinf(xv * f.w);
  } else {
    float4 f = *(const float4*)&invf[d - 128];
    e.x = cosf(xv * f.x); e.y = cosf(xv * f.y);
    e.z = cosf(xv * f.z); e.w = cosf(xv * f.w);
  }
  if (xv == -10.0f) { e.x = 0.f; e.y = 0.f; e.z = 0.f; e.w = 0.f; }
  float4 gv = *(const float4*)&ge[(size_t)g * DD + d];
  float4 o; o.x = gv.x + e.x; o.y = gv.y + e.y; o.z = gv.z + e.z; o.w = gv.w + e.w;
  *(float4*)&h[(size_t)bg * DD + d] = o;
  float s = o.x + o.y + o.z + o.w;
  float s2 = o.x * o.x + o.y * o.y + o.z * o.z + o.w * o.w;
  s += __shfl_xor(s, 1); s += __shfl_xor(s, 2); s += __shfl_xor(s, 4);
  s += __shfl_xor(s, 8); s += __shfl_xor(s, 16); s += __shfl_xor(s, 32);
  s2 += __shfl_xor(s2, 1); s2 += __shfl_xor(s2, 2); s2 += __shfl_xor(s2, 4);
  s2 += __shfl_xor(s2, 8); s2 += __shfl_xor(s2, 16); s2 += __shfl_xor(s2, 32);
  float mn = s * (1.0f / 256.0f);
  float rstd = rsqrtf(s2 * (1.0f / 256.0f) - mn * mn + 1e-5f);
  float4 gm = *(const float4*)&gamma[d];
  float4 bt = *(const float4*)&beta[d];
  short4 pk;
  pk.x = f2bf((o.x - mn) * rstd * gm.x + bt.x);
  pk.y = f2bf((o.y - mn) * rstd * gm.y + bt.y);
  pk.z = f2bf((o.z - mn) * rstd * gm.z + bt.z);
  pk.w = f2bf((o.w - mn) * rstd * gm.w + bt.w);
  short* tb = hnT + (size_t)(bg >> 7) * 32768 + (size_t)(d >> 5) * 4096 +
              ((((d >> 3) & 3) * 128) + (bg & 127)) * 8 + (d & 7);
  *(short4*)tb = pk;
}

// ---------------- weight convert+transpose -> TILED --------------------------
__global__ __launch_bounds__(256) void prep_weights(
    const float* __restrict__ Wq, const float* __restrict__ Wk,
    const float* __restrict__ Wv, const float* __restrict__ WU,
    const float* __restrict__ WV,
    short* __restrict__ TQ, short* __restrict__ TK, short* __restrict__ TV,
    short* __restrict__ TU, short* __restrict__ TVd) {
  int zz = blockIdx.z, l = blockIdx.y;
  const float* src; short* dst; int Kd, Nd;
  if (zz == 0) { src = Wq; dst = TQ; Kd = 256; Nd = 256; }
  else if (zz == 1) { src = Wk; dst = TK; Kd = 256; Nd = 256; }
  else if (zz == 2) { src = Wv; dst = TV; Kd = 256; Nd = 256; }
  else if (zz == 3) { src = WU; dst = TU; Kd = 256; Nd = 1024; }
  else { src = WV; dst = TVd; Kd = 1024; Nd = 256; }
  int tot = Kd * Nd;
  int e = blockIdx.x * 256 + threadIdx.x;
  if (e >= tot) return;
  int t = e >> 12;
  int cslot = (e >> 3) & 511;
  int elem = e & 7;
  int kc8 = cslot >> 7, rn = cslot & 127;
  int nKb = Kd >> 5;
  int nt = t / nKb, kb = t - nt * nKb;
  int n = nt * 128 + rn, k = kb * 32 + kc8 * 8 + elem;
  dst[(size_t)l * tot + e] = f2bf(src[(size_t)l * tot + (size_t)k * Nd + n]);
}

// ---------------- bf16 MFMA GEMM (tiled operands, compile-time K) -------------
template <int K, int EPI>
__global__ __launch_bounds__(256) void gemm_t(
    const short* __restrict__ A, const short* __restrict__ B0,
    const short* __restrict__ B1, const short* __restrict__ B2,
    const float* __restrict__ bias0, const float* __restrict__ bias1,
    const float* __restrict__ bias2,
    short* __restrict__ o0, short* __restrict__ o1, short* __restrict__ o2,
    float* __restrict__ outf, int N) {
  __shared__ __align__(16) short L[24576];  // 48KB
  constexpr int nIter = K / 32;
  int z = blockIdx.z;
  const short* Bt = (z == 0) ? B0 : (z == 1) ? B1 : B2;
  const float* bias = (z == 0) ? bias0 : (z == 1) ? bias1 : bias2;
  short* outz = (z == 0) ? o0 : (z == 1) ? o1 : o2;
  int m0 = blockIdx.x * 128, n0 = blockIdx.y * 128;
  int tid = threadIdx.x;
  int lane = tid & 63, w = tid >> 6;
  int q = lane >> 4, r = lane & 15;
  int wm = (w >> 1) * 64, wn = (w & 1) * 64;
  const short* At = A + (size_t)blockIdx.x * nIter * 4096;
  const short* Btl = Bt + (size_t)blockIdx.y * nIter * 4096;
  f32x4 vzero = {0.f, 0.f, 0.f, 0.f};
  f32x4 acc[4][4];
#pragma unroll
  for (int i = 0; i < 4; ++i)
#pragma unroll
    for (int j = 0; j < 4; ++j) acc[i][j] = vzero;

  int c0 = tid * 8, c1 = (tid + 256) * 8;
#pragma unroll
  for (int g = 0; g < 3; ++g) {
    gld16(At + g * 4096 + c0, &L[g * 4096 + c0]);
    gld16(At + g * 4096 + c1, &L[g * 4096 + c1]);
    gld16(Btl + g * 4096 + c0, &L[12288 + g * 4096 + c0]);
    gld16(Btl + g * 4096 + c1, &L[12288 + g * 4096 + c1]);
  }

  int abase = (q * 128 + wm + r) * 8;
  int bbase = (q * 128 + wn + r) * 8;

#pragma unroll
  for (int gi = 0; gi < nIter; ++gi) {
    const int rem = nIter - 1 - gi;
    if (rem >= 2)      __builtin_amdgcn_s_waitcnt(0x0f78);  // vmcnt(8)
    else if (rem == 1) __builtin_amdgcn_s_waitcnt(0x0f74);  // vmcnt(4)
    else               __builtin_amdgcn_s_waitcnt(0x0f70);  // vmcnt(0)
    __builtin_amdgcn_s_barrier();
    __builtin_amdgcn_s_setprio(1);
    const int cur = gi % 3;
    const short* Asc = &L[cur * 4096];
    const short* Bsc = &L[12288 + cur * 4096];
    bf16x8 af[4], bfr[4];
#pragma unroll
    for (int mt = 0; mt < 4; ++mt)
      af[mt] = *(const bf16x8*)&Asc[abase + mt * 16 * 8];
#pragma unroll
    for (int nt = 0; nt < 4; ++nt)
      bfr[nt] = *(const bf16x8*)&Bsc[bbase + nt * 16 * 8];
#pragma unroll
    for (int mt = 0; mt < 4; ++mt)
#pragma unroll
      for (int nt = 0; nt < 4; ++nt)
        acc[mt][nt] = __builtin_amdgcn_mfma_f32_16x16x32_bf16(bfr[nt], af[mt], acc[mt][nt], 0, 0, 0);
    __builtin_amdgcn_s_setprio(0);
    __builtin_amdgcn_s_waitcnt(0xc07f);  // lgkmcnt(0)
    __builtin_amdgcn_s_barrier();
    if (gi + 3 < nIter) {
      size_t kn = (size_t)(gi + 3) * 4096;
      gld16(At + kn + c0, &L[cur * 4096 + c0]);
      gld16(At + kn + c1, &L[cur * 4096 + c1]);
      gld16(Btl + kn + c0, &L[12288 + cur * 4096 + c0]);
      gld16(Btl + kn + c1, &L[12288 + cur * 4096 + c1]);
    }
  }

  float4 bias4[4];
#pragma unroll
  for (int nt = 0; nt < 4; ++nt) bias4[nt] = *(const float4*)&bias[n0 + wn + nt * 16 + q * 4];

  if (EPI == 0) {
    short* T = L;
#pragma unroll
    for (int mt = 0; mt < 4; ++mt) {
      int ml = wm + mt * 16 + r;
#pragma unroll
      for (int nt = 0; nt < 4; ++nt) {
        f32x4 v = acc[mt][nt];
        v[0] += bias4[nt].x; v[1] += bias4[nt].y; v[2] += bias4[nt].z; v[3] += bias4[nt].w;
        if (z < 2) { v[0] *= v[0]; v[1] *= v[1]; v[2] *= v[2]; v[3] *= v[3]; }
        short4 pk; pk.x = f2bf(v[0]); pk.y = f2bf(v[1]); pk.z = f2bf(v[2]); pk.w = f2bf(v[3]);
        *(short4*)&T[ml * 132 + wn + nt * 16 + q * 4] = pk;
      }
    }
    __syncthreads();
#pragma unroll
    for (int t2 = 0; t2 < 2; ++t2) {
      int task = tid + t2 * 256;
      int row = task & 127, hl = task >> 7;
      size_t obase = ((size_t)((n0 >> 5) + hl) * NROWS + m0 + row) * 32;
#pragma unroll
      for (int j = 0; j < 4; ++j)
        *(bf16x8*)&outz[obase + j * 8] = *(const bf16x8*)&T[row * 132 + hl * 32 + j * 8];
    }
  } else if (EPI == 1) {
#pragma unroll
    for (int mt = 0; mt < 4; ++mt) {
      int ml = wm + mt * 16 + r;
#pragma unroll
      for (int nt = 0; nt < 4; ++nt) {
        f32x4 v = acc[mt][nt];
        v[0] += bias4[nt].x; v[1] += bias4[nt].y; v[2] += bias4[nt].z; v[3] += bias4[nt].w;
#pragma unroll
        for (int e = 0; e < 4; ++e) v[e] = fast_gelu(v[e]);
        short4 o; o.x = f2bf(v[0]); o.y = f2bf(v[1]); o.z = f2bf(v[2]); o.w = f2bf(v[3]);
        int n = n0 + wn + nt * 16 + q * 4;
        size_t ti = ((size_t)blockIdx.x * (N >> 5) + (n >> 5)) * 4096 +
                    (size_t)(((n >> 3) & 3) << 10) + (ml << 3) + (n & 7);
        *(short4*)&outz[ti] = o;
      }
    }
  } else {
    float* TF = (float*)L;
#pragma unroll
    for (int half = 0; half < 2; ++half) {
      __syncthreads();
      if ((w & 1) == half) {
#pragma unroll
        for (int mt = 0; mt < 4; ++mt) {
          int ml = wm + mt * 16 + r;
#pragma unroll
          for (int nt = 0; nt < 4; ++nt) {
            f32x4 v = acc[mt][nt];
            v[0] += bias4[nt].x; v[1] += bias4[nt].y; v[2] += bias4[nt].z; v[3] += bias4[nt].w;
            *(f32x4*)&TF[ml * 68 + nt * 16 + q * 4] = v;
          }
        }
      }
      __syncthreads();
      int row = tid >> 1, col = (tid & 1) * 32;
      size_t hoff = (size_t)(m0 + row) * N + n0 + half * 64 + col;
#pragma unroll
      for (int j = 0; j < 8; ++j) {
        float4 add = *(const float4*)&TF[row * 68 + col + j * 4];
        float4 cur4 = *(float4*)&outf[hoff + j * 4];
        cur4.x += add.x; cur4.y += add.y; cur4.z += add.z; cur4.w += add.w;
        *(float4*)&outf[hoff + j * 4] = cur4;
      }
    }
  }
}

// ---------------- fused FFN: h += gelu(hn@WU+bU)@WV + bV, LN1[l+1] / out -----
__global__ __launch_bounds__(512) void ffn_fused(
    const short* __restrict__ A, const short* __restrict__ TUw,
    const short* __restrict__ TVw, const float* __restrict__ bUp,
    const float* __restrict__ bVp, float* __restrict__ h,
    short* __restrict__ hnT, const float* __restrict__ ln1g,
    const float* __restrict__ ln1b, const float* __restrict__ Woutp,
    const float* __restrict__ boutp, float* __restrict__ outp) {
  __shared__ __align__(16) short L[81920];  // 160KB
  int tid = threadIdx.x;
  int lane = tid & 63, w = tid >> 6;
  int q = lane >> 4, r = lane & 15;
  int wmU = (w >> 2) * 64, wnU = (w & 3) * 32;
  int wmD = (w >> 2) * 64, wnD = (w & 3) * 64;
  const short* At = A + (size_t)blockIdx.x * 32768;

#pragma unroll
  for (int i = 0; i < 8; ++i)
    gld16(At + (i * 512 + tid) * 8, &L[(i * 512 + tid) * 8]);

  auto issueFor = [&](int t) {
    short* dst = &L[49152 + (t & 1) * 16384];
    int ss = t >> 2, pp = t & 3;
    if (pp < 2) {
      const short* g0 = TUw + ((size_t)ss * 8 + pp * 4) * 4096;
#pragma unroll
      for (int i = 0; i < 4; ++i)
        gld16(g0 + (i * 512 + tid) * 8, dst + (i * 512 + tid) * 8);
    } else {
      int kbg0 = ss * 4 + (pp - 2) * 2;
#pragma unroll
      for (int kl = 0; kl < 2; ++kl) {
        gld16(TVw + (size_t)(kbg0 + kl) * 4096 + tid * 8,
              dst + kl * 8192 + tid * 8);
        gld16(TVw + (size_t)(32 + kbg0 + kl) * 4096 + tid * 8,
              dst + kl * 8192 + 4096 + tid * 8);
      }
    }
  };

  issueFor(0); issueFor(1);

  f32x4 vzero = {0.f, 0.f, 0.f, 0.f};
  f32x4 accm[4][2], acco[4][4];
#pragma unroll
  for (int mt = 0; mt < 4; ++mt) {
#pragma unroll
    for (int nt = 0; nt < 2; ++nt) accm[mt][nt] = vzero;
#pragma unroll
    for (int nt = 0; nt < 4; ++nt) acco[mt][nt] = vzero;
  }
  float4 b4[2];

  auto slice = [&](int s, auto lastc) {
    constexpr bool LAST = decltype(lastc)::value;
#pragma unroll
    for (int p = 0; p < 2; ++p) {
      int sig = s * 4 + p;
      __builtin_amdgcn_s_waitcnt(0x0f74);  // vmcnt(4)
      __builtin_amdgcn_s_barrier();
      const short* Ws = &L[49152 + (sig & 1) * 16384];
#pragma unroll
      for (int kl = 0; kl < 4; ++kl) {
        int kb = p * 4 + kl;
        bf16x8 af[4], bfr[2];
#pragma unroll
        for (int mt = 0; mt < 4; ++mt)
          af[mt] = *(const bf16x8*)&L[kb * 4096 + (q * 128 + wmU + mt * 16 + r) * 8];
#pragma unroll
        for (int nt = 0; nt < 2; ++nt)
          bfr[nt] = *(const bf16x8*)&Ws[kl * 4096 + (q * 128 + wnU + nt * 16 + r) * 8];
#pragma unroll
        for (int mt = 0; mt < 4; ++mt)
#pragma unroll
          for (int nt = 0; nt < 2; ++nt)
            accm[mt][nt] = __builtin_amdgcn_mfma_f32_16x16x32_bf16(
                bfr[nt], af[mt], accm[mt][nt], 0, 0, 0);
      }
      if (p == 1) {
#pragma unroll
        for (int mt = 0; mt < 4; ++mt) {
          int row = wmU + mt * 16 + r;
#pragma unroll
          for (int nt = 0; nt < 2; ++nt) {
            f32x4 v = accm[mt][nt];
            float4 bb = b4[nt];
            v[0] += bb.x; v[1] += bb.y; v[2] += bb.z; v[3] += bb.w;
            short4 pk;
            pk.x = f2bf(fast_gelu(v[0])); pk.y = f2bf(fast_gelu(v[1]));
            pk.z = f2bf(fast_gelu(v[2])); pk.w = f2bf(fast_gelu(v[3]));
            int kc8 = 2 * nt + (q >> 1);
            *(short4*)&L[32768 + (w & 3) * 4096 + (kc8 * 128 + row) * 8 + (q & 1) * 4] = pk;
            accm[mt][nt] = vzero;
          }
        }
      }
      __builtin_amdgcn_s_waitcnt(0xc07f);  // lgkmcnt(0)
      __builtin_amdgcn_s_barrier();
      if (p == 0) {
        b4[0] = *(const float4*)&bUp[s * 128 + wnU + q * 4];
        b4[1] = *(const float4*)&bUp[s * 128 + wnU + 16 + q * 4];
      }
      if (sig + 2 < 32) issueFor(sig + 2);
    }
#pragma unroll
    for (int p2 = 0; p2 < 2; ++p2) {
      int sig = s * 4 + 2 + p2;
      if (LAST && p2 == 1) __builtin_amdgcn_s_waitcnt(0x0f70);  // vmcnt(0)
      else                 __builtin_amdgcn_s_waitcnt(0x0f74);  // vmcnt(4)
      __builtin_amdgcn_s_barrier();
      const short* Ws = &L[49152 + (sig & 1) * 16384];
#pragma unroll
      for (int kl = 0; kl < 2; ++kl) {
        int mtile = p2 * 2 + kl;
        bf16x8 am[4], bvf[4];
#pragma unroll
        for (int mt = 0; mt < 4; ++mt)
          am[mt] = *(const bf16x8*)&L[32768 + mtile * 4096 + (q * 128 + wmD + mt * 16 + r) * 8];
#pragma unroll
        for (int nt = 0; nt < 4; ++nt)
          bvf[nt] = *(const bf16x8*)&Ws[kl * 8192 + (wnD >> 7) * 4096 +
                                        (q * 128 + (wnD & 127) + nt * 16 + r) * 8];
#pragma unroll
        for (int mt = 0; mt < 4; ++mt)
#pragma unroll
          for (int nt = 0; nt < 4; ++nt)
            acco[mt][nt] = __builtin_amdgcn_mfma_f32_16x16x32_bf16(
                bvf[nt], am[mt], acco[mt][nt], 0, 0, 0);
      }
      __builtin_amdgcn_s_waitcnt(0xc07f);  // lgkmcnt(0)
      __builtin_amdgcn_s_barrier();
      if (sig + 2 < 32) issueFor(sig + 2);
    }
  };

  for (int s = 0; s < 7; ++s) slice(s, FalseT{});
  slice(7, TrueT{});

  // ---- epilogue: out += bV; TF[128][268]; wave-owns-row h RMW; LN1 or out ----
  float* TF = (float*)L;
  float* MEAN = (float*)&L[68608];
  float* RSTD = MEAN + 128;
  float4 bv4[4];
#pragma unroll
  for (int nt = 0; nt < 4; ++nt) bv4[nt] = *(const float4*)&bVp[wnD + nt * 16 + q * 4];
#pragma unroll
  for (int mt = 0; mt < 4; ++mt) {
    int row = wmD + mt * 16 + r;
#pragma unroll
    for (int nt = 0; nt < 4; ++nt) {
      f32x4 v = acco[mt][nt];
      v[0] += bv4[nt].x; v[1] += bv4[nt].y; v[2] += bv4[nt].z; v[3] += bv4[nt].w;
      *(f32x4*)&TF[row * 268 + wnD + nt * 16 + q * 4] = v;
    }
  }
  __syncthreads();
  float bo = outp ? boutp[0] : 0.f;
#pragma unroll
  for (int p = 0; p < 16; ++p) {
    int row = p * 8 + w;
    int col = lane * 4;
    size_t off = ((size_t)blockIdx.x * 128 + row) * DD + col;
    float4 ad = *(const float4*)&TF[row * 268 + col];
    float4 cv = *(float4*)&h[off];
    cv.x += ad.x; cv.y += ad.y; cv.z += ad.z; cv.w += ad.w;
    *(float4*)&h[off] = cv;
    if (ln1g) {
      *(float4*)&TF[row * 268 + col] = cv;
      float s = cv.x + cv.y + cv.z + cv.w;
      float s2 = cv.x * cv.x + cv.y * cv.y + cv.z * cv.z + cv.w * cv.w;
      s += __shfl_xor(s, 1); s += __shfl_xor(s, 2); s += __shfl_xor(s, 4);
      s += __shfl_xor(s, 8); s += __shfl_xor(s, 16); s += __shfl_xor(s, 32);
      s2 += __shfl_xor(s2, 1); s2 += __shfl_xor(s2, 2); s2 += __shfl_xor(s2, 4);
      s2 += __shfl_xor(s2, 8); s2 += __shfl_xor(s2, 16); s2 += __shfl_xor(s2, 32);
      if (lane == 0) {
        float mn = s * (1.0f / 256.0f);
        MEAN[row] = mn;
        RSTD[row] = rsqrtf(s2 * (1.0f / 256.0f) - mn * mn + 1e-5f);
      }
    }
    if (outp) {
      float4 w4 = *(const float4*)&Woutp[col];
      float so = cv.x * w4.x + cv.y * w4.y + cv.z * w4.z + cv.w * w4.w;
      so += __shfl_xor(so, 1); so += __shfl_xor(so, 2); so += __shfl_xor(so, 4);
      so += __shfl_xor(so, 8); so += __shfl_xor(so, 16); so += __shfl_xor(so, 32);
      if (lane == 0) outp[(size_t)blockIdx.x * 128 + row] = so + bo;
    }
  }
  if (ln1g) {
    __syncthreads();
    int row2 = tid & 127, kc8g = tid >> 7;
    float mn = MEAN[row2], rstd = RSTD[row2];
    short* tb = hnT + (size_t)blockIdx.x * 32768 + (kc8g * 128 + row2) * 8;
#pragma unroll
    for (int kb = 0; kb < 8; ++kb) {
      int k0 = kb * 32 + kc8g * 8;
      float4 x0 = *(const float4*)&TF[row2 * 268 + k0];
      float4 x1 = *(const float4*)&TF[row2 * 268 + k0 + 4];
      float4 g0 = *(const float4*)&ln1g[k0], g1 = *(const float4*)&ln1g[k0 + 4];
      float4 b0 = *(const float4*)&ln1b[k0], b1 = *(const float4*)&ln1b[k0 + 4];
      bf16x8 aw;
      aw[0] = f2bf((x0.x - mn) * rstd * g0.x + b0.x);
      aw[1] = f2bf((x0.y - mn) * rstd * g0.y + b0.y);
      aw[2] = f2bf((x0.z - mn) * rstd * g0.z + b0.z);
      aw[3] = f2bf((x0.w - mn) * rstd * g0.w + b0.w);
      aw[4] = f2bf((x1.x - mn) * rstd * g1.x + b1.x);
      aw[5] = f2bf((x1.y - mn) * rstd * g1.y + b1.y);
      aw[6] = f2bf((x1.z - mn) * rstd * g1.z + b1.z);
      aw[7] = f2bf((x1.w - mn) * rstd * g1.w + b1.w);
      *(bf16x8*)&tb[(size_t)kb * 4096] = aw;
    }
  }
}

// ---------------- attention A1: per (b,h,chunk) S_c = K^T V, z_c = sum k ------
__global__ __launch_bounds__(256) void attn_chunk_kv(
    const short* __restrict__ Kb, const short* __restrict__ Vb,
    float* __restrict__ St, float* __restrict__ Zc) {
  __shared__ short Kt[4][32 * 72];
  __shared__ short Vt[4][32 * 72];
  int wid = threadIdx.x >> 6;
  int blk = blockIdx.x * 4 + wid;
  int c = blk & (NC - 1), bh = blk >> 5;
  int b = bh >> 3, hh = bh & 7;
  int lane = threadIdx.x & 63, q = lane >> 4, r = lane & 15;
  size_t rowbase = ((size_t)hh * NROWS + b * GG + c * CS + lane) * 32;
#pragma unroll
  for (int j = 0; j < 4; ++j) {
    bf16x8 kv = *(const bf16x8*)&Kb[rowbase + j * 8];
    bf16x8 vv = *(const bf16x8*)&Vb[rowbase + j * 8];
#pragma unroll
    for (int e = 0; e < 8; ++e) {
      Kt[wid][(j * 8 + e) * 72 + lane] = kv[e];
      Vt[wid][(j * 8 + e) * 72 + lane] = vv[e];
    }
  }
  __syncthreads();
  f32x4 vzero = {0.f, 0.f, 0.f, 0.f};
  f32x4 acc[2][2];
#pragma unroll
  for (int i = 0; i < 2; ++i)
#pragma unroll
    for (int j = 0; j < 2; ++j) acc[i][j] = vzero;
#pragma unroll
  for (int ks = 0; ks < 2; ++ks) {
    bf16x8 afr[2], bfr[2];
#pragma unroll
    for (int mt = 0; mt < 2; ++mt) afr[mt] = *(const bf16x8*)&Kt[wid][(mt * 16 + r) * 72 + ks * 32 + q * 8];
#pragma unroll
    for (int nt = 0; nt < 2; ++nt) bfr[nt] = *(const bf16x8*)&Vt[wid][(nt * 16 + r) * 72 + ks * 32 + q * 8];
#pragma unroll
    for (int mt = 0; mt < 2; ++mt)
#pragma unroll
      for (int nt = 0; nt < 2; ++nt)
        acc[mt][nt] = __builtin_amdgcn_mfma_f32_16x16x32_bf16(afr[mt], bfr[nt], acc[mt][nt], 0, 0, 0);
  }
  float* stp = St + ((size_t)bh * NC + c) * 1024;
#pragma unroll
  for (int mt = 0; mt < 2; ++mt)
#pragma unroll
    for (int nt = 0; nt < 2; ++nt)
      *(f32x4*)&stp[(nt * 16 + r) * 32 + mt * 16 + q * 4] = acc[mt][nt];  // St[d][f]
  if (lane < 32) {
    float s = 0.f;
#pragma unroll
    for (int j = 0; j < 8; ++j) {
      bf16x8 kr = *(const bf16x8*)&Kt[wid][lane * 72 + j * 8];
#pragma unroll
      for (int e = 0; e < 8; ++e) s += bf2f(kr[e]);
    }
    Zc[((size_t)bh * NC + c) * 32 + lane] = s;
  }
}

// ---------------- attention A2: exclusive prefix over chunks ------------------
__global__ __launch_bounds__(1024) void attn_prefix(float* __restrict__ St, float* __restrict__ Zc) {
  int bh = blockIdx.x, i = threadIdx.x;
  float run = 0.f;
  float* p = St + (size_t)bh * NC * 1024 + i;
#pragma unroll
  for (int c = 0; c < NC; ++c) { float t = p[(size_t)c * 1024]; p[(size_t)c * 1024] = run; run += t; }
  if (i < 32) {
    float rz = 0.f;
    float* pz = Zc + (size_t)bh * NC * 32 + i;
#pragma unroll
    for (int c = 0; c < NC; ++c) { float t = pz[c * 32]; pz[c * 32] = rz; rz += t; }
  }
}

// ---------------- attention B: intra-chunk + apply + fused LN2 ---------------
__global__ __launch_bounds__(512) void attn_intra(
    const short* __restrict__ Qb, const short* __restrict__ Kb,
    const short* __restrict__ Vb, const float* __restrict__ St,
    const float* __restrict__ Zc, float* __restrict__ h,
    short* __restrict__ hnT, const float* __restrict__ ln2g,
    const float* __restrict__ ln2b) {
  __shared__ __align__(16) short P[8][64 * 72];
  __shared__ short Vt[8][32 * 72];
  __shared__ float den[8][64];
  __shared__ float MEAN[64], RSTD[64];
  int wid = threadIdx.x >> 6;
  int u = blockIdx.x;
  int b = u >> 5, c = u & 31;
  int hh = wid, bh = b * 8 + hh;
  int lane = threadIdx.x & 63, q = lane >> 4, r = lane & 15;
  size_t hrow0 = (size_t)b * GG + c * CS;
  size_t qrow0 = (size_t)hh * NROWS + b * GG + c * CS;

  const float* zp = Zc + ((size_t)bh * NC + c) * 32;
  float qz = 0.f;
  {
    size_t qoff = (qrow0 + lane) * 32;
#pragma unroll
    for (int j = 0; j < 4; ++j) {
      bf16x8 qv = *(const bf16x8*)&Qb[qoff + j * 8];
#pragma unroll
      for (int e = 0; e < 8; ++e) qz += bf2f(qv[e]) * zp[j * 8 + e];
    }
  }
  den[wid][lane] = qz;

  {
    size_t voff = (qrow0 + lane) * 32;
#pragma unroll
    for (int j = 0; j < 4; ++j) {
      bf16x8 vv = *(const bf16x8*)&Vb[voff + j * 8];
#pragma unroll
      for (int e = 0; e < 8; ++e) Vt[wid][(j * 8 + e) * 72 + lane] = vv[e];
    }
  }

  bf16x8 ak[4], bqf[4];
#pragma unroll
  for (int t4 = 0; t4 < 4; ++t4) {
    ak[t4]  = *(const bf16x8*)&Kb[(qrow0 + t4 * 16 + r) * 32 + q * 8];
    bqf[t4] = *(const bf16x8*)&Qb[(qrow0 + t4 * 16 + r) * 32 + q * 8];
  }
  f32x4 vzero = {0.f, 0.f, 0.f, 0.f};
  f32x4 pacc[4][4];
#pragma unroll
  for (int mt = 0; mt < 4; ++mt)
#pragma unroll
    for (int nt = 0; nt < 4; ++nt)
      pacc[mt][nt] = __builtin_amdgcn_mfma_f32_16x16x32_bf16(ak[mt], bqf[nt], vzero, 0, 0, 0);

  float rs[4] = {0.f, 0.f, 0.f, 0.f};
#pragma unroll
  for (int nt = 0; nt < 4; ++nt) {
    int t = nt * 16 + r;
#pragma unroll
    for (int mt = 0; mt < 4; ++mt) {
      short4 pk;
#pragma unroll
      for (int rr = 0; rr < 4; ++rr) {
        int s = mt * 16 + q * 4 + rr;
        float pv = (s <= t) ? pacc[mt][nt][rr] : 0.f;
        rs[nt] += pv;
        ((short*)&pk)[rr] = f2bf(pv);
      }
      *(short4*)&P[wid][t * 72 + mt * 16 + q * 4] = pk;
    }
  }
#pragma unroll
  for (int nt = 0; nt < 4; ++nt) {
    rs[nt] += __shfl_xor(rs[nt], 16);
    rs[nt] += __shfl_xor(rs[nt], 32);
  }
  __syncthreads();
  if (lane < 16) {
#pragma unroll
    for (int nt = 0; nt < 4; ++nt) den[wid][nt * 16 + lane] += rs[nt];
  }
  __syncthreads();

  f32x4 oacc[4][2];
#pragma unroll
  for (int mt = 0; mt < 4; ++mt)
#pragma unroll
    for (int nt2 = 0; nt2 < 2; ++nt2) oacc[mt][nt2] = vzero;
  const float* stp = St + ((size_t)bh * NC + c) * 1024;
#pragma unroll
  for (int nt2 = 0; nt2 < 2; ++nt2) {
    float4 s0 = *(const float4*)&stp[(nt2 * 16 + r) * 32 + q * 8];
    float4 s1 = *(const float4*)&stp[(nt2 * 16 + r) * 32 + q * 8 + 4];
    bf16x8 bs;
    bs[0] = f2bf(s0.x); bs[1] = f2bf(s0.y); bs[2] = f2bf(s0.z); bs[3] = f2bf(s0.w);
    bs[4] = f2bf(s1.x); bs[5] = f2bf(s1.y); bs[6] = f2bf(s1.z); bs[7] = f2bf(s1.w);
#pragma unroll
    for (int mt = 0; mt < 4; ++mt)
      oacc[mt][nt2] = __builtin_amdgcn_mfma_f32_16x16x32_bf16(bqf[mt], bs, oacc[mt][nt2], 0, 0, 0);
  }
#pragma unroll
  for (int ks = 0; ks < 2; ++ks) {
    bf16x8 ap[4];
#pragma unroll
    for (int mt = 0; mt < 4; ++mt)
      ap[mt] = *(const bf16x8*)&P[wid][(mt * 16 + r) * 72 + ks * 32 + q * 8];
#pragma unroll
    for (int nt2 = 0; nt2 < 2; ++nt2) {
      bf16x8 bv_ = *(const bf16x8*)&Vt[wid][(nt2 * 16 + r) * 72 + ks * 32 + q * 8];
#pragma unroll
      for (int mt = 0; mt < 4; ++mt)
        oacc[mt][nt2] = __builtin_amdgcn_mfma_f32_16x16x32_bf16(ap[mt], bv_, oacc[mt][nt2], 0, 0, 0);
    }
  }

  // ---- epilogue: OF[64][268] f32 (aliases P); h RMW + LN2 + tiled hn ----
  float* OF = (float*)&P[0][0];
  __syncthreads();
#pragma unroll
  for (int mt = 0; mt < 4; ++mt) {
#pragma unroll
    for (int rr = 0; rr < 4; ++rr) {
      int t = mt * 16 + q * 4 + rr;
      float inv = 1.0f / (den[wid][t] + 1e-16f);
#pragma unroll
      for (int nt2 = 0; nt2 < 2; ++nt2)
        OF[t * 268 + hh * 32 + nt2 * 16 + r] = oacc[mt][nt2][rr] * inv;
    }
  }
  __syncthreads();
  int tid = threadIdx.x;
#pragma unroll
  for (int p = 0; p < 8; ++p) {
    int row = p * 8 + wid;
    int col = lane * 4;
    size_t off = (hrow0 + row) * DD + col;
    float4 ad = *(const float4*)&OF[row * 268 + col];
    float4 cv = *(float4*)&h[off];
    cv.x += ad.x; cv.y += ad.y; cv.z += ad.z; cv.w += ad.w;
    *(float4*)&h[off] = cv;
    *(float4*)&OF[row * 268 + col] = cv;
    float s = cv.x + cv.y + cv.z + cv.w;
    float s2 = cv.x * cv.x + cv.y * cv.y + cv.z * cv.z + cv.w * cv.w;
    s += __shfl_xor(s, 1); s += __shfl_xor(s, 2); s += __shfl_xor(s, 4);
    s += __shfl_xor(s, 8); s += __shfl_xor(s, 16); s += __shfl_xor(s, 32);
    s2 += __shfl_xor(s2, 1); s2 += __shfl_xor(s2, 2); s2 += __shfl_xor(s2, 4);
    s2 += __shfl_xor(s2, 8); s2 += __shfl_xor(s2, 16); s2 += __shfl_xor(s2, 32);
    if (lane == 0) {
      float mn = s * (1.0f / 256.0f);
      MEAN[row] = mn;
      RSTD[row] = rsqrtf(s2 * (1.0f / 256.0f) - mn * mn + 1e-5f);
    }
  }
  __syncthreads();
  int row2 = tid & 63, kc8g = (tid >> 6) & 3, half = tid >> 8;
  float mn = MEAN[row2], rstd = RSTD[row2];
  size_t grow = hrow0 + row2;
  short* tb = hnT + (grow >> 7) * 32768 + (kc8g * 128 + (int)(grow & 127)) * 8;
#pragma unroll
  for (int j = 0; j < 4; ++j) {
    int kb = half * 4 + j;
    int k0 = kb * 32 + kc8g * 8;
    float4 x0 = *(const float4*)&OF[row2 * 268 + k0];
    float4 x1 = *(const float4*)&OF[row2 * 268 + k0 + 4];
    float4 g0 = *(const float4*)&ln2g[k0], g1 = *(const float4*)&ln2g[k0 + 4];
    float4 b0 = *(const float4*)&ln2b[k0], b1 = *(const float4*)&ln2b[k0 + 4];
    bf16x8 aw;
    aw[0] = f2bf((x0.x - mn) * rstd * g0.x + b0.x);
    aw[1] = f2bf((x0.y - mn) * rstd * g0.y + b0.y);
    aw[2] = f2bf((x0.z - mn) * rstd * g0.z + b0.z);
    aw[3] = f2bf((x0.w - mn) * rstd * g0.w + b0.w);
    aw[4] = f2bf((x1.x - mn) * rstd * g1.x + b1.x);
    aw[5] = f2bf((x1.y - mn) * rstd * g1.y + b1.y);
    aw[6] = f2bf((x1.z - mn) * rstd * g1.z + b1.z);
    aw[7] = f2bf((x1.w - mn) * rstd * g1.w + b1.w);
    *(bf16x8*)&tb[(size_t)kb * 4096] = aw;
  }
}

extern "C" void kernel_launch(void* const* d_in, const int* in_sizes, int n_in,
                              void* d_out, int out_size, void* d_ws, size_t ws_size,
                              hipStream_t stream) {
  const float* x    = (const float*)d_in[0];
  const float* ge   = (const float*)d_in[1];
  const float* invf = (const float*)d_in[2];
  const float* Wq   = (const float*)d_in[3];
  const float* bq   = (const float*)d_in[4];
  const float* Wk   = (const float*)d_in[5];
  const float* bk   = (const float*)d_in[6];
  const float* Wv   = (const float*)d_in[7];
  const float* bv   = (const float*)d_in[8];
  const float* ln1g = (const float*)d_in[9];
  const float* ln1b = (const float*)d_in[10];
  const float* ln2g = (const float*)d_in[11];
  const float* ln2b = (const float*)d_in[12];
  const float* WU   = (const float*)d_in[13];
  const float* bU   = (const float*)d_in[14];
  const float* WV   = (const float*)d_in[15];
  const float* bV   = (const float*)d_in[16];
  const float* Wout = (const float*)d_in[17];
  const float* bout = (const float*)d_in[18];
  float* out = (float*)d_out;

  char* ws = (char*)d_ws;
  float* h   = (float*)(ws + 0);            // 33.5 MB
  short* hn  = (short*)(ws + 33554432);     // 16.8 MB (tiled)
  char*  R   = ws + 50331648;               // shared region
  short* qb  = (short*)(R + 0);             // head-major [8][32768][32]
  short* kb  = (short*)(R + 16777216);
  short* vb  = (short*)(R + 33554432);
  float* St  = (float*)(R + 50331648);
  float* Zc  = (float*)(R + 67108864);
  char*  WT  = R + 67633152;
  short* TQ  = (short*)(WT + 0);
  short* TK  = (short*)(WT + 524288);
  short* TVq = (short*)(WT + 1048576);
  short* TU  = (short*)(WT + 1572864);
  short* TVd = (short*)(WT + 3670016);

  prep_weights<<<dim3(1024, 4, 5), 256, 0, stream>>>(Wq, Wk, Wv, WU, WV, TQ, TK, TVq, TU, TVd);
  embed_ln<<<NROWS / 4, 256, 0, stream>>>(x, ge, invf, ln1g, ln1b, h, hn);

  for (int l = 0; l < 4; ++l) {
    gemm_t<256, 0><<<dim3(256, 2, 3), 256, 0, stream>>>(
        hn, TQ + l * 65536, TK + l * 65536, TVq + l * 65536,
        bq + l * 256, bk + l * 256, bv + l * 256,
        qb, kb, vb, nullptr, 256);
    attn_chunk_kv<<<1024, 256, 0, stream>>>(kb, vb, St, Zc);
    attn_prefix<<<128, 1024, 0, stream>>>(St, Zc);
    attn_intra<<<512, 512, 0, stream>>>(qb, kb, vb, St, Zc, h,
                                        hn, ln2g + l * 256, ln2b + l * 256);
    ffn_fused<<<256, 512, 0, stream>>>(hn, TU + l * 262144, TVd + l * 262144,
                                       bU + l * 1024, bV + l * 256, h,
                                       hn,
                                       (l < 3) ? ln1g + (l + 1) * 256 : nullptr,
                                       (l < 3) ? ln1b + (l + 1) * 256 : nullptr,
                                       (l == 3) ? Wout : nullptr,
                                       (l == 3) ? bout : nullptr,
                                       (l == 3) ? out : nullptr);
  }
}

// Round 13
// 692.281 us; speedup vs baseline: 2.0566x; 1.0094x over previous
//
#include <hip/hip_runtime.h>
#include <math.h>

// ExpressionPerformer: B=16,G=2048,D=256,H=8,dh=32,FFN=1024,L=4
// Round-22 (= R21 + critical-path reorganization, compute loops untouched):
//  - QKV gemm split: KV-gemm dispatch (z in {0,1}, sqmask squares K only) then
//    gemm_q_prefix: grid 640 = 512 Q-gemm blocks (verified gemm body, square)
//    + 128 prefix blocks (verified scan, 256thr x 4 streams, bit-identical
//    order). chunk_kv starts ~10us earlier; prefix's ~8us hides under Q-gemm.
//    No fences, no intra-grid deps (prefix reads previous dispatch's St/Zc).
//  - Dispatches unchanged (22); per-layer critical path shortened.

#define GG 2048
#define DD 256
#define NROWS 32768
#define NC 32
#define CS 64

typedef __attribute__((ext_vector_type(8))) short bf16x8;
typedef __attribute__((ext_vector_type(4))) float f32x4;

struct FalseT { static constexpr bool value = false; };
struct TrueT  { static constexpr bool value = true;  };

__device__ __forceinline__ short f2bf(float f) {
  union { float f; unsigned u; } v; v.f = f;
  unsigned r = v.u + 0x7FFFu + ((v.u >> 16) & 1u);
  return (short)(r >> 16);
}
__device__ __forceinline__ float bf2f(short s) {
  union { unsigned u; float f; } v; v.u = ((unsigned)(unsigned short)s) << 16;
  return v.f;
}
__device__ __forceinline__ void gld16(const short* g, short* l) {
  __builtin_amdgcn_global_load_lds(
      (const __attribute__((address_space(1))) void*)g,
      (__attribute__((address_space(3))) void*)l, 16, 0, 0);
}
__device__ __forceinline__ float fast_gelu(float x) {
  float y = 1.595769122f * (x + 0.044715f * x * x * x);
  return x / (1.0f + __expf(-y));
}

// ---------------- embed + layer-0 LN1 ---------------------------------------
__global__ __launch_bounds__(256) void embed_ln(
    const float* __restrict__ x, const float* __restrict__ ge,
    const float* __restrict__ invf, const float* __restrict__ gamma,
    const float* __restrict__ beta, float* __restrict__ h,
    short* __restrict__ hnT) {
  int bg = blockIdx.x * 4 + (threadIdx.x >> 6);
  int g = bg & (GG - 1);
  int lane = threadIdx.x & 63;
  float xv = x[bg];
  int d = lane * 4;
  float4 e;
  if (lane < 32) {
    float4 f = *(const float4*)&invf[d];
    e.x = sinf(xv * f.x); e.y = sinf(xv * f.y);
    e.z = sinf(xv * f.z); e.w = sinf(xv * f.w);
  } else {
    float4 f = *(const float4*)&invf[d - 128];
    e.x = cosf(xv * f.x); e.y = cosf(xv * f.y);
    e.z = cosf(xv * f.z); e.w = cosf(xv * f.w);
  }
  if (xv == -10.0f) { e.x = 0.f; e.y = 0.f; e.z = 0.f; e.w = 0.f; }
  float4 gv = *(const float4*)&ge[(size_t)g * DD + d];
  float4 o; o.x = gv.x + e.x; o.y = gv.y + e.y; o.z = gv.z + e.z; o.w = gv.w + e.w;
  *(float4*)&h[(size_t)bg * DD + d] = o;
  float s = o.x + o.y + o.z + o.w;
  float s2 = o.x * o.x + o.y * o.y + o.z * o.z + o.w * o.w;
  s += __shfl_xor(s, 1); s += __shfl_xor(s, 2); s += __shfl_xor(s, 4);
  s += __shfl_xor(s, 8); s += __shfl_xor(s, 16); s += __shfl_xor(s, 32);
  s2 += __shfl_xor(s2, 1); s2 += __shfl_xor(s2, 2); s2 += __shfl_xor(s2, 4);
  s2 += __shfl_xor(s2, 8); s2 += __shfl_xor(s2, 16); s2 += __shfl_xor(s2, 32);
  float mn = s * (1.0f / 256.0f);
  float rstd = rsqrtf(s2 * (1.0f / 256.0f) - mn * mn + 1e-5f);
  float4 gm = *(const float4*)&gamma[d];
  float4 bt = *(const float4*)&beta[d];
  short4 pk;
  pk.x = f2bf((o.x - mn) * rstd * gm.x + bt.x);
  pk.y = f2bf((o.y - mn) * rstd * gm.y + bt.y);
  pk.z = f2bf((o.z - mn) * rstd * gm.z + bt.z);
  pk.w = f2bf((o.w - mn) * rstd * gm.w + bt.w);
  short* tb = hnT + (size_t)(bg >> 7) * 32768 + (size_t)(d >> 5) * 4096 +
              ((((d >> 3) & 3) * 128) + (bg & 127)) * 8 + (d & 7);
  *(short4*)tb = pk;
}

// ---------------- weight convert+transpose -> TILED --------------------------
__global__ __launch_bounds__(256) void prep_weights(
    const float* __restrict__ Wq, const float* __restrict__ Wk,
    const float* __restrict__ Wv, const float* __restrict__ WU,
    const float* __restrict__ WV,
    short* __restrict__ TQ, short* __restrict__ TK, short* __restrict__ TV,
    short* __restrict__ TU, short* __restrict__ TVd) {
  int zz = blockIdx.z, l = blockIdx.y;
  const float* src; short* dst; int Kd, Nd;
  if (zz == 0) { src = Wq; dst = TQ; Kd = 256; Nd = 256; }
  else if (zz == 1) { src = Wk; dst = TK; Kd = 256; Nd = 256; }
  else if (zz == 2) { src = Wv; dst = TV; Kd = 256; Nd = 256; }
  else if (zz == 3) { src = WU; dst = TU; Kd = 256; Nd = 1024; }
  else { src = WV; dst = TVd; Kd = 1024; Nd = 256; }
  int tot = Kd * Nd;
  int e = blockIdx.x * 256 + threadIdx.x;
  if (e >= tot) return;
  int t = e >> 12;
  int cslot = (e >> 3) & 511;
  int elem = e & 7;
  int kc8 = cslot >> 7, rn = cslot & 127;
  int nKb = Kd >> 5;
  int nt = t / nKb, kb = t - nt * nKb;
  int n = nt * 128 + rn, k = kb * 32 + kc8 * 8 + elem;
  dst[(size_t)l * tot + e] = f2bf(src[(size_t)l * tot + (size_t)k * Nd + n]);
}

// ---------------- bf16 MFMA GEMM (tiled operands; KV dispatch) ---------------
// EPI 0 only user now: head-major bf16 out via LDS transpose; square per
// sqmask bit z.
template <int K, int EPI>
__global__ __launch_bounds__(256) void gemm_t(
    const short* __restrict__ A, const short* __restrict__ B0,
    const short* __restrict__ B1, const short* __restrict__ B2,
    const float* __restrict__ bias0, const float* __restrict__ bias1,
    const float* __restrict__ bias2,
    short* __restrict__ o0, short* __restrict__ o1, short* __restrict__ o2,
    float* __restrict__ outf, int N, int sqmask) {
  __shared__ __align__(16) short L[24576];  // 48KB
  constexpr int nIter = K / 32;
  int z = blockIdx.z;
  const short* Bt = (z == 0) ? B0 : (z == 1) ? B1 : B2;
  const float* bias = (z == 0) ? bias0 : (z == 1) ? bias1 : bias2;
  short* outz = (z == 0) ? o0 : (z == 1) ? o1 : o2;
  int m0 = blockIdx.x * 128, n0 = blockIdx.y * 128;
  int tid = threadIdx.x;
  int lane = tid & 63, w = tid >> 6;
  int q = lane >> 4, r = lane & 15;
  int wm = (w >> 1) * 64, wn = (w & 1) * 64;
  const short* At = A + (size_t)blockIdx.x * nIter * 4096;
  const short* Btl = Bt + (size_t)blockIdx.y * nIter * 4096;
  f32x4 vzero = {0.f, 0.f, 0.f, 0.f};
  f32x4 acc[4][4];
#pragma unroll
  for (int i = 0; i < 4; ++i)
#pragma unroll
    for (int j = 0; j < 4; ++j) acc[i][j] = vzero;

  int c0 = tid * 8, c1 = (tid + 256) * 8;
#pragma unroll
  for (int g = 0; g < 3; ++g) {
    gld16(At + g * 4096 + c0, &L[g * 4096 + c0]);
    gld16(At + g * 4096 + c1, &L[g * 4096 + c1]);
    gld16(Btl + g * 4096 + c0, &L[12288 + g * 4096 + c0]);
    gld16(Btl + g * 4096 + c1, &L[12288 + g * 4096 + c1]);
  }

  int abase = (q * 128 + wm + r) * 8;
  int bbase = (q * 128 + wn + r) * 8;

#pragma unroll
  for (int gi = 0; gi < nIter; ++gi) {
    const int rem = nIter - 1 - gi;
    if (rem >= 2)      __builtin_amdgcn_s_waitcnt(0x0f78);  // vmcnt(8)
    else if (rem == 1) __builtin_amdgcn_s_waitcnt(0x0f74);  // vmcnt(4)
    else               __builtin_amdgcn_s_waitcnt(0x0f70);  // vmcnt(0)
    __builtin_amdgcn_s_barrier();
    __builtin_amdgcn_s_setprio(1);
    const int cur = gi % 3;
    const short* Asc = &L[cur * 4096];
    const short* Bsc = &L[12288 + cur * 4096];
    bf16x8 af[4], bfr[4];
#pragma unroll
    for (int mt = 0; mt < 4; ++mt)
      af[mt] = *(const bf16x8*)&Asc[abase + mt * 16 * 8];
#pragma unroll
    for (int nt = 0; nt < 4; ++nt)
      bfr[nt] = *(const bf16x8*)&Bsc[bbase + nt * 16 * 8];
#pragma unroll
    for (int mt = 0; mt < 4; ++mt)
#pragma unroll
      for (int nt = 0; nt < 4; ++nt)
        acc[mt][nt] = __builtin_amdgcn_mfma_f32_16x16x32_bf16(bfr[nt], af[mt], acc[mt][nt], 0, 0, 0);
    __builtin_amdgcn_s_setprio(0);
    __builtin_amdgcn_s_waitcnt(0xc07f);  // lgkmcnt(0)
    __builtin_amdgcn_s_barrier();
    if (gi + 3 < nIter) {
      size_t kn = (size_t)(gi + 3) * 4096;
      gld16(At + kn + c0, &L[cur * 4096 + c0]);
      gld16(At + kn + c1, &L[cur * 4096 + c1]);
      gld16(Btl + kn + c0, &L[12288 + cur * 4096 + c0]);
      gld16(Btl + kn + c1, &L[12288 + cur * 4096 + c1]);
    }
  }

  float4 bias4[4];
#pragma unroll
  for (int nt = 0; nt < 4; ++nt) bias4[nt] = *(const float4*)&bias[n0 + wn + nt * 16 + q * 4];

  {
    short* T = L;
    bool sq = (sqmask >> z) & 1;
#pragma unroll
    for (int mt = 0; mt < 4; ++mt) {
      int ml = wm + mt * 16 + r;
#pragma unroll
      for (int nt = 0; nt < 4; ++nt) {
        f32x4 v = acc[mt][nt];
        v[0] += bias4[nt].x; v[1] += bias4[nt].y; v[2] += bias4[nt].z; v[3] += bias4[nt].w;
        if (sq) { v[0] *= v[0]; v[1] *= v[1]; v[2] *= v[2]; v[3] *= v[3]; }
        short4 pk; pk.x = f2bf(v[0]); pk.y = f2bf(v[1]); pk.z = f2bf(v[2]); pk.w = f2bf(v[3]);
        *(short4*)&T[ml * 132 + wn + nt * 16 + q * 4] = pk;
      }
    }
    __syncthreads();
#pragma unroll
    for (int t2 = 0; t2 < 2; ++t2) {
      int task = tid + t2 * 256;
      int row = task & 127, hl = task >> 7;
      size_t obase = ((size_t)((n0 >> 5) + hl) * NROWS + m0 + row) * 32;
#pragma unroll
      for (int j = 0; j < 4; ++j)
        *(bf16x8*)&outz[obase + j * 8] = *(const bf16x8*)&T[row * 132 + hl * 32 + j * 8];
    }
  }
}

// ---------------- fused Q-gemm + attn_prefix ---------------------------------
// Grid 640 x 256thr: blocks 0..511 = Q projection (gemm body, square, EPI 0
// head-major out); blocks 512..639 = exclusive prefix for bh = bid-512
// (4 positions/thread, same serial order as the old 1024-thr attn_prefix).
__global__ __launch_bounds__(256) void gemm_q_prefix(
    const short* __restrict__ A, const short* __restrict__ Bq,
    const float* __restrict__ biasq, short* __restrict__ oq,
    float* __restrict__ St, float* __restrict__ Zc) {
  __shared__ __align__(16) short L[24576];  // 48KB (unused by prefix blocks)
  int bid = blockIdx.x;
  if (bid >= 512) {  // ---- prefix part ----
    int bh = bid - 512;
    int t = threadIdx.x;
    float* p = St + (size_t)bh * NC * 1024;
    float* p0 = p + t;
    float* p1 = p + t + 256;
    float* p2 = p + t + 512;
    float* p3 = p + t + 768;
    float r0 = 0.f, r1 = 0.f, r2 = 0.f, r3 = 0.f;
#pragma unroll
    for (int c2 = 0; c2 < NC; ++c2) {
      float v0 = p0[c2 * 1024], v1 = p1[c2 * 1024];
      float v2 = p2[c2 * 1024], v3 = p3[c2 * 1024];
      p0[c2 * 1024] = r0; p1[c2 * 1024] = r1;
      p2[c2 * 1024] = r2; p3[c2 * 1024] = r3;
      r0 += v0; r1 += v1; r2 += v2; r3 += v3;
    }
    if (t < 32) {
      float rz = 0.f;
      float* pz = Zc + (size_t)bh * NC * 32 + t;
#pragma unroll
      for (int c2 = 0; c2 < NC; ++c2) { float v = pz[c2 * 32]; pz[c2 * 32] = rz; rz += v; }
    }
    return;
  }
  // ---- Q-gemm part (identical structure to gemm_t, z=0, square) ----
  constexpr int nIter = 8;  // K=256
  int m0 = (bid >> 1) * 128, n0 = (bid & 1) * 128;
  int tid = threadIdx.x;
  int lane = tid & 63, w = tid >> 6;
  int q = lane >> 4, r = lane & 15;
  int wm = (w >> 1) * 64, wn = (w & 1) * 64;
  const short* At = A + (size_t)(bid >> 1) * nIter * 4096;
  const short* Btl = Bq + (size_t)(bid & 1) * nIter * 4096;
  f32x4 vzero = {0.f, 0.f, 0.f, 0.f};
  f32x4 acc[4][4];
#pragma unroll
  for (int i = 0; i < 4; ++i)
#pragma unroll
    for (int j = 0; j < 4; ++j) acc[i][j] = vzero;

  int c0 = tid * 8, c1 = (tid + 256) * 8;
#pragma unroll
  for (int g = 0; g < 3; ++g) {
    gld16(At + g * 4096 + c0, &L[g * 4096 + c0]);
    gld16(At + g * 4096 + c1, &L[g * 4096 + c1]);
    gld16(Btl + g * 4096 + c0, &L[12288 + g * 4096 + c0]);
    gld16(Btl + g * 4096 + c1, &L[12288 + g * 4096 + c1]);
  }

  int abase = (q * 128 + wm + r) * 8;
  int bbase = (q * 128 + wn + r) * 8;

#pragma unroll
  for (int gi = 0; gi < nIter; ++gi) {
    const int rem = nIter - 1 - gi;
    if (rem >= 2)      __builtin_amdgcn_s_waitcnt(0x0f78);  // vmcnt(8)
    else if (rem == 1) __builtin_amdgcn_s_waitcnt(0x0f74);  // vmcnt(4)
    else               __builtin_amdgcn_s_waitcnt(0x0f70);  // vmcnt(0)
    __builtin_amdgcn_s_barrier();
    __builtin_amdgcn_s_setprio(1);
    const int cur = gi % 3;
    const short* Asc = &L[cur * 4096];
    const short* Bsc = &L[12288 + cur * 4096];
    bf16x8 af[4], bfr[4];
#pragma unroll
    for (int mt = 0; mt < 4; ++mt)
      af[mt] = *(const bf16x8*)&Asc[abase + mt * 16 * 8];
#pragma unroll
    for (int nt = 0; nt < 4; ++nt)
      bfr[nt] = *(const bf16x8*)&Bsc[bbase + nt * 16 * 8];
#pragma unroll
    for (int mt = 0; mt < 4; ++mt)
#pragma unroll
      for (int nt = 0; nt < 4; ++nt)
        acc[mt][nt] = __builtin_amdgcn_mfma_f32_16x16x32_bf16(bfr[nt], af[mt], acc[mt][nt], 0, 0, 0);
    __builtin_amdgcn_s_setprio(0);
    __builtin_amdgcn_s_waitcnt(0xc07f);  // lgkmcnt(0)
    __builtin_amdgcn_s_barrier();
    if (gi + 3 < nIter) {
      size_t kn = (size_t)(gi + 3) * 4096;
      gld16(At + kn + c0, &L[cur * 4096 + c0]);
      gld16(At + kn + c1, &L[cur * 4096 + c1]);
      gld16(Btl + kn + c0, &L[12288 + cur * 4096 + c0]);
      gld16(Btl + kn + c1, &L[12288 + cur * 4096 + c1]);
    }
  }

  float4 bias4[4];
#pragma unroll
  for (int nt = 0; nt < 4; ++nt) bias4[nt] = *(const float4*)&biasq[n0 + wn + nt * 16 + q * 4];

  short* T = L;
#pragma unroll
  for (int mt = 0; mt < 4; ++mt) {
    int ml = wm + mt * 16 + r;
#pragma unroll
    for (int nt = 0; nt < 4; ++nt) {
      f32x4 v = acc[mt][nt];
      v[0] += bias4[nt].x; v[1] += bias4[nt].y; v[2] += bias4[nt].z; v[3] += bias4[nt].w;
      v[0] *= v[0]; v[1] *= v[1]; v[2] *= v[2]; v[3] *= v[3];  // square (Q)
      short4 pk; pk.x = f2bf(v[0]); pk.y = f2bf(v[1]); pk.z = f2bf(v[2]); pk.w = f2bf(v[3]);
      *(short4*)&T[ml * 132 + wn + nt * 16 + q * 4] = pk;
    }
  }
  __syncthreads();
#pragma unroll
  for (int t2 = 0; t2 < 2; ++t2) {
    int task = tid + t2 * 256;
    int row = task & 127, hl = task >> 7;
    size_t obase = ((size_t)((n0 >> 5) + hl) * NROWS + m0 + row) * 32;
#pragma unroll
    for (int j = 0; j < 4; ++j)
      *(bf16x8*)&oq[obase + j * 8] = *(const bf16x8*)&T[row * 132 + hl * 32 + j * 8];
  }
}

// ---------------- fused FFN: h += gelu(hn@WU+bU)@WV + bV, LN1[l+1] / out -----
__global__ __launch_bounds__(512) void ffn_fused(
    const short* __restrict__ A, const short* __restrict__ TUw,
    const short* __restrict__ TVw, const float* __restrict__ bUp,
    const float* __restrict__ bVp, float* __restrict__ h,
    short* __restrict__ hnT, const float* __restrict__ ln1g,
    const float* __restrict__ ln1b, const float* __restrict__ Woutp,
    const float* __restrict__ boutp, float* __restrict__ outp) {
  __shared__ __align__(16) short L[81920];  // 160KB
  int tid = threadIdx.x;
  int lane = tid & 63, w = tid >> 6;
  int q = lane >> 4, r = lane & 15;
  int wmU = (w >> 2) * 64, wnU = (w & 3) * 32;
  int wmD = (w >> 2) * 64, wnD = (w & 3) * 64;
  const short* At = A + (size_t)blockIdx.x * 32768;

#pragma unroll
  for (int i = 0; i < 8; ++i)
    gld16(At + (i * 512 + tid) * 8, &L[(i * 512 + tid) * 8]);

  auto issueFor = [&](int t) {
    short* dst = &L[49152 + (t & 1) * 16384];
    int ss = t >> 2, pp = t & 3;
    if (pp < 2) {
      const short* g0 = TUw + ((size_t)ss * 8 + pp * 4) * 4096;
#pragma unroll
      for (int i = 0; i < 4; ++i)
        gld16(g0 + (i * 512 + tid) * 8, dst + (i * 512 + tid) * 8);
    } else {
      int kbg0 = ss * 4 + (pp - 2) * 2;
#pragma unroll
      for (int kl = 0; kl < 2; ++kl) {
        gld16(TVw + (size_t)(kbg0 + kl) * 4096 + tid * 8,
              dst + kl * 8192 + tid * 8);
        gld16(TVw + (size_t)(32 + kbg0 + kl) * 4096 + tid * 8,
              dst + kl * 8192 + 4096 + tid * 8);
      }
    }
  };

  issueFor(0); issueFor(1);

  f32x4 vzero = {0.f, 0.f, 0.f, 0.f};
  f32x4 accm[4][2], acco[4][4];
#pragma unroll
  for (int mt = 0; mt < 4; ++mt) {
#pragma unroll
    for (int nt = 0; nt < 2; ++nt) accm[mt][nt] = vzero;
#pragma unroll
    for (int nt = 0; nt < 4; ++nt) acco[mt][nt] = vzero;
  }
  float4 b4[2];

  auto slice = [&](int s, auto lastc) {
    constexpr bool LAST = decltype(lastc)::value;
#pragma unroll
    for (int p = 0; p < 2; ++p) {
      int sig = s * 4 + p;
      __builtin_amdgcn_s_waitcnt(0x0f74);  // vmcnt(4)
      __builtin_amdgcn_s_barrier();
      const short* Ws = &L[49152 + (sig & 1) * 16384];
#pragma unroll
      for (int kl = 0; kl < 4; ++kl) {
        int kb = p * 4 + kl;
        bf16x8 af[4], bfr[2];
#pragma unroll
        for (int mt = 0; mt < 4; ++mt)
          af[mt] = *(const bf16x8*)&L[kb * 4096 + (q * 128 + wmU + mt * 16 + r) * 8];
#pragma unroll
        for (int nt = 0; nt < 2; ++nt)
          bfr[nt] = *(const bf16x8*)&Ws[kl * 4096 + (q * 128 + wnU + nt * 16 + r) * 8];
#pragma unroll
        for (int mt = 0; mt < 4; ++mt)
#pragma unroll
          for (int nt = 0; nt < 2; ++nt)
            accm[mt][nt] = __builtin_amdgcn_mfma_f32_16x16x32_bf16(
                bfr[nt], af[mt], accm[mt][nt], 0, 0, 0);
      }
      if (p == 1) {
#pragma unroll
        for (int mt = 0; mt < 4; ++mt) {
          int row = wmU + mt * 16 + r;
#pragma unroll
          for (int nt = 0; nt < 2; ++nt) {
            f32x4 v = accm[mt][nt];
            float4 bb = b4[nt];
            v[0] += bb.x; v[1] += bb.y; v[2] += bb.z; v[3] += bb.w;
            short4 pk;
            pk.x = f2bf(fast_gelu(v[0])); pk.y = f2bf(fast_gelu(v[1]));
            pk.z = f2bf(fast_gelu(v[2])); pk.w = f2bf(fast_gelu(v[3]));
            int kc8 = 2 * nt + (q >> 1);
            *(short4*)&L[32768 + (w & 3) * 4096 + (kc8 * 128 + row) * 8 + (q & 1) * 4] = pk;
            accm[mt][nt] = vzero;
          }
        }
      }
      __builtin_amdgcn_s_waitcnt(0xc07f);  // lgkmcnt(0)
      __builtin_amdgcn_s_barrier();
      if (p == 0) {
        b4[0] = *(const float4*)&bUp[s * 128 + wnU + q * 4];
        b4[1] = *(const float4*)&bUp[s * 128 + wnU + 16 + q * 4];
      }
      if (sig + 2 < 32) issueFor(sig + 2);
    }
#pragma unroll
    for (int p2 = 0; p2 < 2; ++p2) {
      int sig = s * 4 + 2 + p2;
      if (LAST && p2 == 1) __builtin_amdgcn_s_waitcnt(0x0f70);  // vmcnt(0)
      else                 __builtin_amdgcn_s_waitcnt(0x0f74);  // vmcnt(4)
      __builtin_amdgcn_s_barrier();
      const short* Ws = &L[49152 + (sig & 1) * 16384];
#pragma unroll
      for (int kl = 0; kl < 2; ++kl) {
        int mtile = p2 * 2 + kl;
        bf16x8 am[4], bvf[4];
#pragma unroll
        for (int mt = 0; mt < 4; ++mt)
          am[mt] = *(const bf16x8*)&L[32768 + mtile * 4096 + (q * 128 + wmD + mt * 16 + r) * 8];
#pragma unroll
        for (int nt = 0; nt < 4; ++nt)
          bvf[nt] = *(const bf16x8*)&Ws[kl * 8192 + (wnD >> 7) * 4096 +
                                        (q * 128 + (wnD & 127) + nt * 16 + r) * 8];
#pragma unroll
        for (int mt = 0; mt < 4; ++mt)
#pragma unroll
          for (int nt = 0; nt < 4; ++nt)
            acco[mt][nt] = __builtin_amdgcn_mfma_f32_16x16x32_bf16(
                bvf[nt], am[mt], acco[mt][nt], 0, 0, 0);
      }
      __builtin_amdgcn_s_waitcnt(0xc07f);  // lgkmcnt(0)
      __builtin_amdgcn_s_barrier();
      if (sig + 2 < 32) issueFor(sig + 2);
    }
  };

  for (int s = 0; s < 7; ++s) slice(s, FalseT{});
  slice(7, TrueT{});

  // ---- epilogue: out += bV; TF[128][268]; wave-owns-row h RMW; LN1 or out ----
  float* TF = (float*)L;
  float* MEAN = (float*)&L[68608];
  float* RSTD = MEAN + 128;
  float4 bv4[4];
#pragma unroll
  for (int nt = 0; nt < 4; ++nt) bv4[nt] = *(const float4*)&bVp[wnD + nt * 16 + q * 4];
#pragma unroll
  for (int mt = 0; mt < 4; ++mt) {
    int row = wmD + mt * 16 + r;
#pragma unroll
    for (int nt = 0; nt < 4; ++nt) {
      f32x4 v = acco[mt][nt];
      v[0] += bv4[nt].x; v[1] += bv4[nt].y; v[2] += bv4[nt].z; v[3] += bv4[nt].w;
      *(f32x4*)&TF[row * 268 + wnD + nt * 16 + q * 4] = v;
    }
  }
  __syncthreads();
  float bo = outp ? boutp[0] : 0.f;
#pragma unroll
  for (int p = 0; p < 16; ++p) {
    int row = p * 8 + w;
    int col = lane * 4;
    size_t off = ((size_t)blockIdx.x * 128 + row) * DD + col;
    float4 ad = *(const float4*)&TF[row * 268 + col];
    float4 cv = *(float4*)&h[off];
    cv.x += ad.x; cv.y += ad.y; cv.z += ad.z; cv.w += ad.w;
    *(float4*)&h[off] = cv;
    if (ln1g) {
      *(float4*)&TF[row * 268 + col] = cv;
      float s = cv.x + cv.y + cv.z + cv.w;
      float s2 = cv.x * cv.x + cv.y * cv.y + cv.z * cv.z + cv.w * cv.w;
      s += __shfl_xor(s, 1); s += __shfl_xor(s, 2); s += __shfl_xor(s, 4);
      s += __shfl_xor(s, 8); s += __shfl_xor(s, 16); s += __shfl_xor(s, 32);
      s2 += __shfl_xor(s2, 1); s2 += __shfl_xor(s2, 2); s2 += __shfl_xor(s2, 4);
      s2 += __shfl_xor(s2, 8); s2 += __shfl_xor(s2, 16); s2 += __shfl_xor(s2, 32);
      if (lane == 0) {
        float mn = s * (1.0f / 256.0f);
        MEAN[row] = mn;
        RSTD[row] = rsqrtf(s2 * (1.0f / 256.0f) - mn * mn + 1e-5f);
      }
    }
    if (outp) {
      float4 w4 = *(const float4*)&Woutp[col];
      float so = cv.x * w4.x + cv.y * w4.y + cv.z * w4.z + cv.w * w4.w;
      so += __shfl_xor(so, 1); so += __shfl_xor(so, 2); so += __shfl_xor(so, 4);
      so += __shfl_xor(so, 8); so += __shfl_xor(so, 16); so += __shfl_xor(so, 32);
      if (lane == 0) outp[(size_t)blockIdx.x * 128 + row] = so + bo;
    }
  }
  if (ln1g) {
    __syncthreads();
    int row2 = tid & 127, kc8g = tid >> 7;
    float mn = MEAN[row2], rstd = RSTD[row2];
    short* tb = hnT + (size_t)blockIdx.x * 32768 + (kc8g * 128 + row2) * 8;
#pragma unroll
    for (int kb = 0; kb < 8; ++kb) {
      int k0 = kb * 32 + kc8g * 8;
      float4 x0 = *(const float4*)&TF[row2 * 268 + k0];
      float4 x1 = *(const float4*)&TF[row2 * 268 + k0 + 4];
      float4 g0 = *(const float4*)&ln1g[k0], g1 = *(const float4*)&ln1g[k0 + 4];
      float4 b0 = *(const float4*)&ln1b[k0], b1 = *(const float4*)&ln1b[k0 + 4];
      bf16x8 aw;
      aw[0] = f2bf((x0.x - mn) * rstd * g0.x + b0.x);
      aw[1] = f2bf((x0.y - mn) * rstd * g0.y + b0.y);
      aw[2] = f2bf((x0.z - mn) * rstd * g0.z + b0.z);
      aw[3] = f2bf((x0.w - mn) * rstd * g0.w + b0.w);
      aw[4] = f2bf((x1.x - mn) * rstd * g1.x + b1.x);
      aw[5] = f2bf((x1.y - mn) * rstd * g1.y + b1.y);
      aw[6] = f2bf((x1.z - mn) * rstd * g1.z + b1.z);
      aw[7] = f2bf((x1.w - mn) * rstd * g1.w + b1.w);
      *(bf16x8*)&tb[(size_t)kb * 4096] = aw;
    }
  }
}

// ---------------- attention A1: per (b,h,chunk) S_c = K^T V, z_c = sum k ------
__global__ __launch_bounds__(256) void attn_chunk_kv(
    const short* __restrict__ Kb, const short* __restrict__ Vb,
    float* __restrict__ St, float* __restrict__ Zc) {
  __shared__ short Kt[4][32 * 72];
  __shared__ short Vt[4][32 * 72];
  int wid = threadIdx.x >> 6;
  int blk = blockIdx.x * 4 + wid;
  int c = blk & (NC - 1), bh = blk >> 5;
  int b = bh >> 3, hh = bh & 7;
  int lane = threadIdx.x & 63, q = lane >> 4, r = lane & 15;
  size_t rowbase = ((size_t)hh * NROWS + b * GG + c * CS + lane) * 32;
#pragma unroll
  for (int j = 0; j < 4; ++j) {
    bf16x8 kv = *(const bf16x8*)&Kb[rowbase + j * 8];
    bf16x8 vv = *(const bf16x8*)&Vb[rowbase + j * 8];
#pragma unroll
    for (int e = 0; e < 8; ++e) {
      Kt[wid][(j * 8 + e) * 72 + lane] = kv[e];
      Vt[wid][(j * 8 + e) * 72 + lane] = vv[e];
    }
  }
  __syncthreads();
  f32x4 vzero = {0.f, 0.f, 0.f, 0.f};
  f32x4 acc[2][2];
#pragma unroll
  for (int i = 0; i < 2; ++i)
#pragma unroll
    for (int j = 0; j < 2; ++j) acc[i][j] = vzero;
#pragma unroll
  for (int ks = 0; ks < 2; ++ks) {
    bf16x8 afr[2], bfr[2];
#pragma unroll
    for (int mt = 0; mt < 2; ++mt) afr[mt] = *(const bf16x8*)&Kt[wid][(mt * 16 + r) * 72 + ks * 32 + q * 8];
#pragma unroll
    for (int nt = 0; nt < 2; ++nt) bfr[nt] = *(const bf16x8*)&Vt[wid][(nt * 16 + r) * 72 + ks * 32 + q * 8];
#pragma unroll
    for (int mt = 0; mt < 2; ++mt)
#pragma unroll
      for (int nt = 0; nt < 2; ++nt)
        acc[mt][nt] = __builtin_amdgcn_mfma_f32_16x16x32_bf16(afr[mt], bfr[nt], acc[mt][nt], 0, 0, 0);
  }
  float* stp = St + ((size_t)bh * NC + c) * 1024;
#pragma unroll
  for (int mt = 0; mt < 2; ++mt)
#pragma unroll
    for (int nt = 0; nt < 2; ++nt)
      *(f32x4*)&stp[(nt * 16 + r) * 32 + mt * 16 + q * 4] = acc[mt][nt];  // St[d][f]
  if (lane < 32) {
    float s = 0.f;
#pragma unroll
    for (int j = 0; j < 8; ++j) {
      bf16x8 kr = *(const bf16x8*)&Kt[wid][lane * 72 + j * 8];
#pragma unroll
      for (int e = 0; e < 8; ++e) s += bf2f(kr[e]);
    }
    Zc[((size_t)bh * NC + c) * 32 + lane] = s;
  }
}

// ---------------- attention B: intra-chunk + apply + fused LN2 ---------------
__global__ __launch_bounds__(512) void attn_intra(
    const short* __restrict__ Qb, const short* __restrict__ Kb,
    const short* __restrict__ Vb, const float* __restrict__ St,
    const float* __restrict__ Zc, float* __restrict__ h,
    short* __restrict__ hnT, const float* __restrict__ ln2g,
    const float* __restrict__ ln2b) {
  __shared__ __align__(16) short P[8][64 * 72];
  __shared__ short Vt[8][32 * 72];
  __shared__ float den[8][64];
  __shared__ float MEAN[64], RSTD[64];
  int wid = threadIdx.x >> 6;
  int u = blockIdx.x;
  int b = u >> 5, c = u & 31;
  int hh = wid, bh = b * 8 + hh;
  int lane = threadIdx.x & 63, q = lane >> 4, r = lane & 15;
  size_t hrow0 = (size_t)b * GG + c * CS;
  size_t qrow0 = (size_t)hh * NROWS + b * GG + c * CS;

  const float* zp = Zc + ((size_t)bh * NC + c) * 32;
  float qz = 0.f;
  {
    size_t qoff = (qrow0 + lane) * 32;
#pragma unroll
    for (int j = 0; j < 4; ++j) {
      bf16x8 qv = *(const bf16x8*)&Qb[qoff + j * 8];
#pragma unroll
      for (int e = 0; e < 8; ++e) qz += bf2f(qv[e]) * zp[j * 8 + e];
    }
  }
  den[wid][lane] = qz;

  {
    size_t voff = (qrow0 + lane) * 32;
#pragma unroll
    for (int j = 0; j < 4; ++j) {
      bf16x8 vv = *(const bf16x8*)&Vb[voff + j * 8];
#pragma unroll
      for (int e = 0; e < 8; ++e) Vt[wid][(j * 8 + e) * 72 + lane] = vv[e];
    }
  }

  bf16x8 ak[4], bqf[4];
#pragma unroll
  for (int t4 = 0; t4 < 4; ++t4) {
    ak[t4]  = *(const bf16x8*)&Kb[(qrow0 + t4 * 16 + r) * 32 + q * 8];
    bqf[t4] = *(const bf16x8*)&Qb[(qrow0 + t4 * 16 + r) * 32 + q * 8];
  }
  f32x4 vzero = {0.f, 0.f, 0.f, 0.f};
  f32x4 pacc[4][4];
#pragma unroll
  for (int mt = 0; mt < 4; ++mt)
#pragma unroll
    for (int nt = 0; nt < 4; ++nt)
      pacc[mt][nt] = __builtin_amdgcn_mfma_f32_16x16x32_bf16(ak[mt], bqf[nt], vzero, 0, 0, 0);

  float rs[4] = {0.f, 0.f, 0.f, 0.f};
#pragma unroll
  for (int nt = 0; nt < 4; ++nt) {
    int t = nt * 16 + r;
#pragma unroll
    for (int mt = 0; mt < 4; ++mt) {
      short4 pk;
#pragma unroll
      for (int rr = 0; rr < 4; ++rr) {
        int s = mt * 16 + q * 4 + rr;
        float pv = (s <= t) ? pacc[mt][nt][rr] : 0.f;
        rs[nt] += pv;
        ((short*)&pk)[rr] = f2bf(pv);
      }
      *(short4*)&P[wid][t * 72 + mt * 16 + q * 4] = pk;
    }
  }
#pragma unroll
  for (int nt = 0; nt < 4; ++nt) {
    rs[nt] += __shfl_xor(rs[nt], 16);
    rs[nt] += __shfl_xor(rs[nt], 32);
  }
  __syncthreads();
  if (lane < 16) {
#pragma unroll
    for (int nt = 0; nt < 4; ++nt) den[wid][nt * 16 + lane] += rs[nt];
  }
  __syncthreads();

  f32x4 oacc[4][2];
#pragma unroll
  for (int mt = 0; mt < 4; ++mt)
#pragma unroll
    for (int nt2 = 0; nt2 < 2; ++nt2) oacc[mt][nt2] = vzero;
  const float* stp = St + ((size_t)bh * NC + c) * 1024;
#pragma unroll
  for (int nt2 = 0; nt2 < 2; ++nt2) {
    float4 s0 = *(const float4*)&stp[(nt2 * 16 + r) * 32 + q * 8];
    float4 s1 = *(const float4*)&stp[(nt2 * 16 + r) * 32 + q * 8 + 4];
    bf16x8 bs;
    bs[0] = f2bf(s0.x); bs[1] = f2bf(s0.y); bs[2] = f2bf(s0.z); bs[3] = f2bf(s0.w);
    bs[4] = f2bf(s1.x); bs[5] = f2bf(s1.y); bs[6] = f2bf(s1.z); bs[7] = f2bf(s1.w);
#pragma unroll
    for (int mt = 0; mt < 4; ++mt)
      oacc[mt][nt2] = __builtin_amdgcn_mfma_f32_16x16x32_bf16(bqf[mt], bs, oacc[mt][nt2], 0, 0, 0);
  }
#pragma unroll
  for (int ks = 0; ks < 2; ++ks) {
    bf16x8 ap[4];
#pragma unroll
    for (int mt = 0; mt < 4; ++mt)
      ap[mt] = *(const bf16x8*)&P[wid][(mt * 16 + r) * 72 + ks * 32 + q * 8];
#pragma unroll
    for (int nt2 = 0; nt2 < 2; ++nt2) {
      bf16x8 bv_ = *(const bf16x8*)&Vt[wid][(nt2 * 16 + r) * 72 + ks * 32 + q * 8];
#pragma unroll
      for (int mt = 0; mt < 4; ++mt)
        oacc[mt][nt2] = __builtin_amdgcn_mfma_f32_16x16x32_bf16(ap[mt], bv_, oacc[mt][nt2], 0, 0, 0);
    }
  }

  // ---- epilogue: OF[64][268] f32 (aliases P); h RMW + LN2 + tiled hn ----
  float* OF = (float*)&P[0][0];
  __syncthreads();
#pragma unroll
  for (int mt = 0; mt < 4; ++mt) {
#pragma unroll
    for (int rr = 0; rr < 4; ++rr) {
      int t = mt * 16 + q * 4 + rr;
      float inv = 1.0f / (den[wid][t] + 1e-16f);
#pragma unroll
      for (int nt2 = 0; nt2 < 2; ++nt2)
        OF[t * 268 + hh * 32 + nt2 * 16 + r] = oacc[mt][nt2][rr] * inv;
    }
  }
  __syncthreads();
  int tid = threadIdx.x;
#pragma unroll
  for (int p = 0; p < 8; ++p) {
    int row = p * 8 + wid;
    int col = lane * 4;
    size_t off = (hrow0 + row) * DD + col;
    float4 ad = *(const float4*)&OF[row * 268 + col];
    float4 cv = *(float4*)&h[off];
    cv.x += ad.x; cv.y += ad.y; cv.z += ad.z; cv.w += ad.w;
    *(float4*)&h[off] = cv;
    *(float4*)&OF[row * 268 + col] = cv;
    float s = cv.x + cv.y + cv.z + cv.w;
    float s2 = cv.x * cv.x + cv.y * cv.y + cv.z * cv.z + cv.w * cv.w;
    s += __shfl_xor(s, 1); s += __shfl_xor(s, 2); s += __shfl_xor(s, 4);
    s += __shfl_xor(s, 8); s += __shfl_xor(s, 16); s += __shfl_xor(s, 32);
    s2 += __shfl_xor(s2, 1); s2 += __shfl_xor(s2, 2); s2 += __shfl_xor(s2, 4);
    s2 += __shfl_xor(s2, 8); s2 += __shfl_xor(s2, 16); s2 += __shfl_xor(s2, 32);
    if (lane == 0) {
      float mn = s * (1.0f / 256.0f);
      MEAN[row] = mn;
      RSTD[row] = rsqrtf(s2 * (1.0f / 256.0f) - mn * mn + 1e-5f);
    }
  }
  __syncthreads();
  int row2 = tid & 63, kc8g = (tid >> 6) & 3, half = tid >> 8;
  float mn = MEAN[row2], rstd = RSTD[row2];
  size_t grow = hrow0 + row2;
  short* tb = hnT + (grow >> 7) * 32768 + (kc8g * 128 + (int)(grow & 127)) * 8;
#pragma unroll
  for (int j = 0; j < 4; ++j) {
    int kb = half * 4 + j;
    int k0 = kb * 32 + kc8g * 8;
    float4 x0 = *(const float4*)&OF[row2 * 268 + k0];
    float4 x1 = *(const float4*)&OF[row2 * 268 + k0 + 4];
    float4 g0 = *(const float4*)&ln2g[k0], g1 = *(const float4*)&ln2g[k0 + 4];
    float4 b0 = *(const float4*)&ln2b[k0], b1 = *(const float4*)&ln2b[k0 + 4];
    bf16x8 aw;
    aw[0] = f2bf((x0.x - mn) * rstd * g0.x + b0.x);
    aw[1] = f2bf((x0.y - mn) * rstd * g0.y + b0.y);
    aw[2] = f2bf((x0.z - mn) * rstd * g0.z + b0.z);
    aw[3] = f2bf((x0.w - mn) * rstd * g0.w + b0.w);
    aw[4] = f2bf((x1.x - mn) * rstd * g1.x + b1.x);
    aw[5] = f2bf((x1.y - mn) * rstd * g1.y + b1.y);
    aw[6] = f2bf((x1.z - mn) * rstd * g1.z + b1.z);
    aw[7] = f2bf((x1.w - mn) * rstd * g1.w + b1.w);
    *(bf16x8*)&tb[(size_t)kb * 4096] = aw;
  }
}

extern "C" void kernel_launch(void* const* d_in, const int* in_sizes, int n_in,
                              void* d_out, int out_size, void* d_ws, size_t ws_size,
                              hipStream_t stream) {
  const float* x    = (const float*)d_in[0];
  const float* ge   = (const float*)d_in[1];
  const float* invf = (const float*)d_in[2];
  const float* Wq   = (const float*)d_in[3];
  const float* bq   = (const float*)d_in[4];
  const float* Wk   = (const float*)d_in[5];
  const float* bk   = (const float*)d_in[6];
  const float* Wv   = (const float*)d_in[7];
  const float* bv   = (const float*)d_in[8];
  const float* ln1g = (const float*)d_in[9];
  const float* ln1b = (const float*)d_in[10];
  const float* ln2g = (const float*)d_in[11];
  const float* ln2b = (const float*)d_in[12];
  const float* WU   = (const float*)d_in[13];
  const float* bU   = (const float*)d_in[14];
  const float* WV   = (const float*)d_in[15];
  const float* bV   = (const float*)d_in[16];
  const float* Wout = (const float*)d_in[17];
  const float* bout = (const float*)d_in[18];
  float* out = (float*)d_out;

  char* ws = (char*)d_ws;
  float* h   = (float*)(ws + 0);            // 33.5 MB
  short* hn  = (short*)(ws + 33554432);     // 16.8 MB (tiled)
  char*  R   = ws + 50331648;               // shared region
  short* qb  = (short*)(R + 0);             // head-major [8][32768][32]
  short* kb  = (short*)(R + 16777216);
  short* vb  = (short*)(R + 33554432);
  float* St  = (float*)(R + 50331648);
  float* Zc  = (float*)(R + 67108864);
  char*  WT  = R + 67633152;
  short* TQ  = (short*)(WT + 0);
  short* TK  = (short*)(WT + 524288);
  short* TVq = (short*)(WT + 1048576);
  short* TU  = (short*)(WT + 1572864);
  short* TVd = (short*)(WT + 3670016);

  prep_weights<<<dim3(1024, 4, 5), 256, 0, stream>>>(Wq, Wk, Wv, WU, WV, TQ, TK, TVq, TU, TVd);
  embed_ln<<<NROWS / 4, 256, 0, stream>>>(x, ge, invf, ln1g, ln1b, h, hn);

  for (int l = 0; l < 4; ++l) {
    // KV projection: z=0 -> K (square), z=1 -> V (no square)
    gemm_t<256, 0><<<dim3(256, 2, 2), 256, 0, stream>>>(
        hn, TK + l * 65536, TVq + l * 65536, nullptr,
        bk + l * 256, bv + l * 256, nullptr,
        kb, vb, nullptr, nullptr, 256, /*sqmask=*/1);
    attn_chunk_kv<<<1024, 256, 0, stream>>>(kb, vb, St, Zc);
    // Q projection (square) + prefix hidden behind it
    gemm_q_prefix<<<640, 256, 0, stream>>>(hn, TQ + l * 65536, bq + l * 256,
                                           qb, St, Zc);
    attn_intra<<<512, 512, 0, stream>>>(qb, kb, vb, St, Zc, h,
                                        hn, ln2g + l * 256, ln2b + l * 256);
    ffn_fused<<<256, 512, 0, stream>>>(hn, TU + l * 262144, TVd + l * 262144,
                                       bU + l * 1024, bV + l * 256, h,
                                       hn,
                                       (l < 3) ? ln1g + (l + 1) * 256 : nullptr,
                                       (l < 3) ? ln1b + (l + 1) * 256 : nullptr,
                                       (l == 3) ? Wout : nullptr,
                                       (l == 3) ? bout : nullptr,
                                       (l == 3) ? out : nullptr);
  }
}